// Round 2
// baseline (862.027 us; speedup 1.0000x reference)
//
#include <hip/hip_runtime.h>
#include <math.h>

#define TOK 8192
#define DIMN 1024
#define HID 1280
#define NEXP 8
#define NSH 2
#define NSLOT 10
#define RCAP 17408   // 16384 + 8*128 max padding

typedef short s16x8 __attribute__((ext_vector_type(8)));
typedef float f32x4 __attribute__((ext_vector_type(4)));

// f32 -> bf16 RNE
__device__ __forceinline__ unsigned short f2bf(float f) {
  unsigned u = __float_as_uint(f);
  u += 0x7fffu + ((u >> 16) & 1u);
  return (unsigned short)(u >> 16);
}

__device__ __forceinline__ void gl_lds16(const void* g, void* l) {
  typedef __attribute__((address_space(1))) const unsigned int guint;
  typedef __attribute__((address_space(3))) unsigned int luint;
  __builtin_amdgcn_global_load_lds((guint*)g, (luint*)l, 16, 0, 0);
}

// ---------------- init / zero ----------------
__global__ __launch_bounds__(256) void k_zero(int* __restrict__ glist, float* __restrict__ gw,
                                              int* __restrict__ cnt, int* __restrict__ cnt2,
                                              double* __restrict__ ent_acc) {
  int i = blockIdx.x * 256 + threadIdx.x;
  if (i < RCAP) { glist[i] = 0; gw[i] = 0.0f; }
  if (i < NEXP) { cnt[i] = 0; cnt2[i] = 0; }
  if (i == 0) *ent_acc = 0.0;
}

// ---------------- converts ----------------
__global__ __launch_bounds__(256) void k_cvt_x(const float* __restrict__ x,
                                               unsigned short* __restrict__ xb) {
  int i = blockIdx.x * 256 + threadIdx.x;  // 4 elems each; grid covers TOK*DIMN/4
  float4 v = ((const float4*)x)[i];
  ushort4 o;
  o.x = f2bf(v.x); o.y = f2bf(v.y); o.z = f2bf(v.z); o.w = f2bf(v.w);
  ((ushort4*)xb)[i] = o;
}

// w13b[slot][2560][1024]: row r: g=r>>5, which=(r>>4)&1, i=r&15 -> (which?w3:w1) row g*16+i
__global__ __launch_bounds__(256) void k_cvt_w13(const float* __restrict__ w1, const float* __restrict__ w3,
                                                 const float* __restrict__ sw1, const float* __restrict__ sw3,
                                                 unsigned short* __restrict__ w13b) {
  const int r = blockIdx.x;   // 0..2559
  const int s = blockIdx.y;   // 0..9
  const int which = (r >> 4) & 1;
  const int srow = ((r >> 5) << 4) + (r & 15);
  const float* src;
  if (s < NSH) src = (which ? sw3 : sw1) + ((size_t)s * HID + srow) * DIMN;
  else         src = (which ? w3 : w1) + ((size_t)(s - NSH) * HID + srow) * DIMN;
  unsigned short* dst = w13b + ((size_t)s * 2560 + r) * DIMN;
  int c = threadIdx.x * 4;
  float4 v = *(const float4*)(src + c);
  ushort4 o;
  o.x = f2bf(v.x); o.y = f2bf(v.y); o.z = f2bf(v.z); o.w = f2bf(v.w);
  *(ushort4*)(dst + c) = o;
}

__global__ __launch_bounds__(256) void k_cvt_w2(const float* __restrict__ w2, const float* __restrict__ sw2,
                                                unsigned short* __restrict__ w2b) {
  const int d = blockIdx.x;   // 0..1023
  const int s = blockIdx.y;   // 0..9
  const float* src = (s < NSH) ? sw2 + ((size_t)s * DIMN + d) * HID
                               : w2 + ((size_t)(s - NSH) * DIMN + d) * HID;
  unsigned short* dst = w2b + ((size_t)s * DIMN + d) * HID;
  for (int j = threadIdx.x; j < HID / 4; j += 256) {
    float4 v = ((const float4*)src)[j];
    ushort4 o;
    o.x = f2bf(v.x); o.y = f2bf(v.y); o.z = f2bf(v.z); o.w = f2bf(v.w);
    ((ushort4*)dst)[j] = o;
  }
}

// ---------------- gate ----------------
// CRITICAL: must replicate the reference's FLOAT32 semantics. expert_emb is
// std=1.0 so dots have sigma~32; sigmoid saturates to exactly 1.0f for a large
// fraction of (token,expert) pairs, and top_k tie-breaks by LOWEST INDEX.
// Computing this in f64 picks a different expert set on ~45% of tokens.
__global__ __launch_bounds__(256) void k_gate(const float* __restrict__ x, const float* __restrict__ emb,
                                              const float* __restrict__ bias, int* __restrict__ tidx,
                                              float* __restrict__ tw, int* __restrict__ cnt,
                                              double* __restrict__ ent_acc) {
  const int lane = threadIdx.x & 63;
  const int wv = threadIdx.x >> 6;
  const int t = blockIdx.x * 4 + wv;
  const float* xr = x + (size_t)t * DIMN;
  float acc[NEXP];
#pragma unroll
  for (int e = 0; e < NEXP; ++e) acc[e] = 0.0f;
  for (int i = 0; i < DIMN / 64; ++i) {
    float xv = xr[lane + 64 * i];
#pragma unroll
    for (int e = 0; e < NEXP; ++e)
      acc[e] = fmaf(xv, emb[e * DIMN + lane + 64 * i], acc[e]);
  }
#pragma unroll
  for (int e = 0; e < NEXP; ++e) {
#pragma unroll
    for (int off = 32; off > 0; off >>= 1) acc[e] += __shfl_xor(acc[e], off);
  }
  __shared__ double ebuf[4];
  if (lane == 0) {
    float s[NEXP];
#pragma unroll
    for (int e = 0; e < NEXP; ++e) s[e] = 1.0f / (1.0f + expf(-acc[e])) + bias[e];
    int i0 = 0;
    for (int e = 1; e < NEXP; ++e) if (s[e] > s[i0]) i0 = e;   // strict >: lowest index wins ties
    int i1 = -1;
    for (int e = 0; e < NEXP; ++e) {
      if (e == i0) continue;
      if (i1 < 0 || s[e] > s[i1]) i1 = e;
    }
    float v0 = s[i0], v1 = s[i1];
    float inv = 1.0f / (v0 + v1);
    float w0 = v0 * inv, w1 = v1 * inv;
    tidx[2 * t] = i0; tidx[2 * t + 1] = i1;
    tw[2 * t] = w0; tw[2 * t + 1] = w1;
    atomicAdd(&cnt[i0], 1);
    atomicAdd(&cnt[i1], 1);
    ebuf[wv] = -(double)(w0 * logf(w0) + w1 * logf(w1));
  }
  __syncthreads();
  if (threadIdx.x == 0) atomicAdd(ent_acc, ebuf[0] + ebuf[1] + ebuf[2] + ebuf[3]);
}

// ---------------- offsets + tail finalize ----------------
__global__ void k_offsets(const int* __restrict__ cnt, int* __restrict__ roff, int* __restrict__ cpad,
                          const double* __restrict__ ent_acc, float* __restrict__ out_tail) {
  if (threadIdx.x == 0 && blockIdx.x == 0) {
    int off = 0;
    for (int e = 0; e < NEXP; ++e) {
      roff[e] = off;
      int cp = (cnt[e] + 127) & ~127;
      cpad[e] = cp;
      off += cp;
    }
    out_tail[0] = 0.0f;                                // aux_loss
    out_tail[1] = (float)(*ent_acc * (1.0 / TOK));     // routing_entropy
  }
}

// ---------------- scatter tokens into compact per-expert lists ----------------
__global__ __launch_bounds__(256) void k_scatter(const int* __restrict__ tidx, const float* __restrict__ tw,
                                                 const int* __restrict__ roff, int* __restrict__ cnt2,
                                                 int* __restrict__ glist, float* __restrict__ gw) {
  int t = blockIdx.x * 256 + threadIdx.x;
#pragma unroll
  for (int j = 0; j < 2; ++j) {
    int e = tidx[2 * t + j];
    int p = atomicAdd(&cnt2[e], 1);
    int g = roff[e] + p;
    glist[g] = t;
    gw[g] = tw[2 * t + j];
  }
}

// ---------------- GEMM1: h = silu(X@W1^T) * (X@W3^T), W1/W3 interleaved by 16 cols ----------------
__global__ __launch_bounds__(256) void k_gemm1(const unsigned short* __restrict__ xb,
                                               const unsigned short* __restrict__ w13b,
                                               unsigned short* __restrict__ h,
                                               const int* __restrict__ glist,
                                               const int* __restrict__ roff,
                                               const int* __restrict__ cpad) {
  __shared__ __align__(16) unsigned short As[2][4096];
  __shared__ __align__(16) unsigned short Bs[2][4096];
  const int slot = blockIdx.z, yb = blockIdx.y, bx = blockIdx.x;
  const int tid = threadIdx.x;
  int hrow0, tok0, tok1;
  if (slot < NSH) {
    hrow0 = slot * TOK + yb * 128;
    tok0 = yb * 128 + (tid >> 2);
    tok1 = tok0 + 64;
  } else {
    const int e = slot - NSH;
    if (yb * 128 >= cpad[e]) return;
    const int base = roff[e];
    hrow0 = 2 * TOK + base + yb * 128;
    tok0 = glist[base + yb * 128 + (tid >> 2)];
    tok1 = glist[base + yb * 128 + (tid >> 2) + 64];
  }
  const int kc = (tid & 3) * 8;
  const unsigned short* ap0 = xb + (size_t)tok0 * DIMN + kc;
  const unsigned short* ap1 = xb + (size_t)tok1 * DIMN + kc;
  const unsigned short* bp0 = w13b + (size_t)slot * 2560 * DIMN + ((size_t)bx * 128 + (tid >> 2)) * DIMN + kc;
  const unsigned short* bp1 = bp0 + (size_t)64 * DIMN;
  const int wv = tid >> 6, lane = tid & 63;
  const int wm = wv >> 1, wn = wv & 1;
  f32x4 acc[4][4] = {};
#define STAGE1(buf, kt) do {                                  \
    int _ko = (kt) * 32;                                      \
    gl_lds16(ap0 + _ko, &As[buf][wv * 512]);                  \
    gl_lds16(ap1 + _ko, &As[buf][2048 + wv * 512]);           \
    gl_lds16(bp0 + _ko, &Bs[buf][wv * 512]);                  \
    gl_lds16(bp1 + _ko, &Bs[buf][2048 + wv * 512]);           \
  } while (0)
  STAGE1(0, 0);
  const int aoff = (wm * 64 + (lane & 15)) * 32 + (lane >> 4) * 8;
  const int boff = (wn * 64 + (lane & 15)) * 32 + (lane >> 4) * 8;
  int cur = 0;
  for (int kt = 0; kt < DIMN / 32; ++kt) {
    __syncthreads();
    if (kt + 1 < DIMN / 32) STAGE1(cur ^ 1, kt + 1);
    const unsigned short* Ab = &As[cur][aoff];
    const unsigned short* Bb = &Bs[cur][boff];
    s16x8 af[4], bfv[4];
#pragma unroll
    for (int f = 0; f < 4; ++f) af[f] = *(const s16x8*)(Ab + f * 512);
#pragma unroll
    for (int f = 0; f < 4; ++f) bfv[f] = *(const s16x8*)(Bb + f * 512);
#pragma unroll
    for (int i = 0; i < 4; ++i)
#pragma unroll
      for (int j = 0; j < 4; ++j)
        acc[i][j] = __builtin_amdgcn_mfma_f32_16x16x32_bf16(af[i], bfv[j], acc[i][j], 0, 0, 0);
    cur ^= 1;
  }
#undef STAGE1
  const int lr = lane & 15, lq = lane >> 4;
  const int hc0 = bx * 64 + wn * 32;
#pragma unroll
  for (int mf = 0; mf < 4; ++mf) {
    const int rb = hrow0 + wm * 64 + mf * 16 + lq * 4;
#pragma unroll
    for (int p = 0; p < 2; ++p) {
      f32x4 a1 = acc[mf][2 * p];
      f32x4 a3 = acc[mf][2 * p + 1];
      const int hc = hc0 + p * 16 + lr;
#pragma unroll
      for (int r = 0; r < 4; ++r) {
        float u = a1[r];
        float hv = (u / (1.f + __expf(-u))) * a3[r];
        h[(size_t)(rb + r) * HID + hc] = f2bf(hv);
      }
    }
  }
}

// ---------------- GEMM2 shared: out = 0.5*(h0@W2_0^T + h1@W2_1^T), K=2560 concat ----------------
__global__ __launch_bounds__(256) void k_gemm2s(const unsigned short* __restrict__ h,
                                                const unsigned short* __restrict__ w2b,
                                                float* __restrict__ out) {
  __shared__ __align__(16) unsigned short As[2][4096];
  __shared__ __align__(16) unsigned short Bs[2][4096];
  const int yb = blockIdx.y, bx = blockIdx.x, tid = threadIdx.x;
  const int wv = tid >> 6, lane = tid & 63, wm = wv >> 1, wn = wv & 1;
  const int kc = (tid & 3) * 8;
  const int tr = yb * 128 + (tid >> 2);
  const int nr = bx * 128 + (tid >> 2);
  const unsigned short* a0s0 = h + (size_t)tr * HID + kc;
  const unsigned short* a1s0 = h + (size_t)(tr + 64) * HID + kc;
  const unsigned short* a0s1 = h + (size_t)(TOK + tr) * HID + kc;
  const unsigned short* a1s1 = h + (size_t)(TOK + tr + 64) * HID + kc;
  const unsigned short* b0s0 = w2b + (size_t)nr * HID + kc;
  const unsigned short* b1s0 = b0s0 + (size_t)64 * HID;
  const unsigned short* b0s1 = w2b + (size_t)(DIMN + nr) * HID + kc;
  const unsigned short* b1s1 = b0s1 + (size_t)64 * HID;
  f32x4 acc[4][4] = {};
#define STAGE2S(buf, kt) do {                                             \
    int _k0 = (kt) * 32;                                                  \
    int _k = (_k0 < HID) ? _k0 : _k0 - HID;                               \
    const unsigned short* _a0 = (_k0 < HID) ? a0s0 : a0s1;                \
    const unsigned short* _a1 = (_k0 < HID) ? a1s0 : a1s1;                \
    const unsigned short* _b0 = (_k0 < HID) ? b0s0 : b0s1;                \
    const unsigned short* _b1 = (_k0 < HID) ? b1s0 : b1s1;                \
    gl_lds16(_a0 + _k, &As[buf][wv * 512]);                               \
    gl_lds16(_a1 + _k, &As[buf][2048 + wv * 512]);                        \
    gl_lds16(_b0 + _k, &Bs[buf][wv * 512]);                               \
    gl_lds16(_b1 + _k, &Bs[buf][2048 + wv * 512]);                        \
  } while (0)
  STAGE2S(0, 0);
  const int aoff = (wm * 64 + (lane & 15)) * 32 + (lane >> 4) * 8;
  const int boff = (wn * 64 + (lane & 15)) * 32 + (lane >> 4) * 8;
  int cur = 0;
  for (int kt = 0; kt < 2 * HID / 32; ++kt) {
    __syncthreads();
    if (kt + 1 < 2 * HID / 32) STAGE2S(cur ^ 1, kt + 1);
    const unsigned short* Ab = &As[cur][aoff];
    const unsigned short* Bb = &Bs[cur][boff];
    s16x8 af[4], bfv[4];
#pragma unroll
    for (int f = 0; f < 4; ++f) af[f] = *(const s16x8*)(Ab + f * 512);
#pragma unroll
    for (int f = 0; f < 4; ++f) bfv[f] = *(const s16x8*)(Bb + f * 512);
#pragma unroll
    for (int i = 0; i < 4; ++i)
#pragma unroll
      for (int j = 0; j < 4; ++j)
        acc[i][j] = __builtin_amdgcn_mfma_f32_16x16x32_bf16(af[i], bfv[j], acc[i][j], 0, 0, 0);
    cur ^= 1;
  }
#undef STAGE2S
  const int lr = lane & 15, lq = lane >> 4;
#pragma unroll
  for (int mf = 0; mf < 4; ++mf) {
    const int t = yb * 128 + wm * 64 + mf * 16 + lq * 4;
#pragma unroll
    for (int nf = 0; nf < 4; ++nf) {
      const int col = bx * 128 + wn * 64 + nf * 16 + lr;
#pragma unroll
      for (int r = 0; r < 4; ++r)
        out[(size_t)(t + r) * DIMN + col] = 0.5f * acc[mf][nf][r];
    }
  }
}

// ---------------- GEMM2 routed: out[tok] += wgt * (h_e @ W2_e^T) ----------------
__global__ __launch_bounds__(256) void k_gemm2r(const unsigned short* __restrict__ h,
                                                const unsigned short* __restrict__ w2b,
                                                const int* __restrict__ glist,
                                                const float* __restrict__ gw,
                                                const int* __restrict__ roff,
                                                const int* __restrict__ cpad,
                                                float* __restrict__ out) {
  __shared__ __align__(16) unsigned short As[2][4096];
  __shared__ __align__(16) unsigned short Bs[2][4096];
  const int e = blockIdx.z, yb = blockIdx.y, bx = blockIdx.x, tid = threadIdx.x;
  if (yb * 128 >= cpad[e]) return;
  const int base = roff[e];
  const unsigned short* hA = h + (size_t)(2 * TOK + base) * HID;
  const unsigned short* w2s = w2b + (size_t)(NSH + e) * DIMN * HID;
  const int wv = tid >> 6, lane = tid & 63, wm = wv >> 1, wn = wv & 1;
  const int kc = (tid & 3) * 8;
  const unsigned short* ap0 = hA + ((size_t)yb * 128 + (tid >> 2)) * HID + kc;
  const unsigned short* ap1 = ap0 + (size_t)64 * HID;
  const unsigned short* bp0 = w2s + ((size_t)bx * 128 + (tid >> 2)) * HID + kc;
  const unsigned short* bp1 = bp0 + (size_t)64 * HID;
  f32x4 acc[4][4] = {};
#define STAGE2R(buf, kt) do {                                 \
    int _ko = (kt) * 32;                                      \
    gl_lds16(ap0 + _ko, &As[buf][wv * 512]);                  \
    gl_lds16(ap1 + _ko, &As[buf][2048 + wv * 512]);           \
    gl_lds16(bp0 + _ko, &Bs[buf][wv * 512]);                  \
    gl_lds16(bp1 + _ko, &Bs[buf][2048 + wv * 512]);           \
  } while (0)
  STAGE2R(0, 0);
  const int aoff = (wm * 64 + (lane & 15)) * 32 + (lane >> 4) * 8;
  const int boff = (wn * 64 + (lane & 15)) * 32 + (lane >> 4) * 8;
  int cur = 0;
  for (int kt = 0; kt < HID / 32; ++kt) {
    __syncthreads();
    if (kt + 1 < HID / 32) STAGE2R(cur ^ 1, kt + 1);
    const unsigned short* Ab = &As[cur][aoff];
    const unsigned short* Bb = &Bs[cur][boff];
    s16x8 af[4], bfv[4];
#pragma unroll
    for (int f = 0; f < 4; ++f) af[f] = *(const s16x8*)(Ab + f * 512);
#pragma unroll
    for (int f = 0; f < 4; ++f) bfv[f] = *(const s16x8*)(Bb + f * 512);
#pragma unroll
    for (int i = 0; i < 4; ++i)
#pragma unroll
      for (int j = 0; j < 4; ++j)
        acc[i][j] = __builtin_amdgcn_mfma_f32_16x16x32_bf16(af[i], bfv[j], acc[i][j], 0, 0, 0);
    cur ^= 1;
  }
#undef STAGE2R
  const int lr = lane & 15, lq = lane >> 4;
#pragma unroll
  for (int mf = 0; mf < 4; ++mf) {
    const int lrow = yb * 128 + wm * 64 + mf * 16 + lq * 4;
#pragma unroll
    for (int r = 0; r < 4; ++r) {
      const int g = base + lrow + r;
      const int t = glist[g];
      const float wgt = gw[g];
#pragma unroll
      for (int nf = 0; nf < 4; ++nf) {
        const int col = bx * 128 + wn * 64 + nf * 16 + lr;
        atomicAdd(&out[(size_t)t * DIMN + col], wgt * acc[mf][nf][r]);
      }
    }
  }
}

// ---------------- ws layout ----------------
static const size_t OFF_XB    = 0;                                       // TOK*DIMN u16
static const size_t OFF_W13   = OFF_XB + (size_t)TOK * DIMN * 2;         // 10*2560*1024 u16
static const size_t OFF_W2    = OFF_W13 + (size_t)NSLOT * 2560 * DIMN * 2;
static const size_t OFF_H     = OFF_W2 + (size_t)NSLOT * DIMN * HID * 2; // (2*TOK+RCAP)*HID u16
static const size_t OFF_GLIST = OFF_H + (size_t)(2 * TOK + RCAP) * HID * 2;
static const size_t OFF_GW    = OFF_GLIST + (size_t)RCAP * 4;
static const size_t OFF_TIDX  = OFF_GW + (size_t)RCAP * 4;
static const size_t OFF_TW    = OFF_TIDX + (size_t)TOK * 2 * 4;
static const size_t OFF_CNT   = OFF_TW + (size_t)TOK * 2 * 4;
static const size_t OFF_CNT2  = OFF_CNT + 32;
static const size_t OFF_ROFF  = OFF_CNT2 + 32;
static const size_t OFF_CPAD  = OFF_ROFF + 32;
static const size_t OFF_ENT   = OFF_CPAD + 32;

extern "C" void kernel_launch(void* const* d_in, const int* in_sizes, int n_in,
                              void* d_out, int out_size, void* d_ws, size_t ws_size,
                              hipStream_t stream) {
  const float* x    = (const float*)d_in[0];
  const float* emb  = (const float*)d_in[1];
  const float* bias = (const float*)d_in[2];
  const float* w1   = (const float*)d_in[3];
  const float* w2   = (const float*)d_in[4];
  const float* w3   = (const float*)d_in[5];
  const float* sw1  = (const float*)d_in[6];
  const float* sw2  = (const float*)d_in[7];
  const float* sw3  = (const float*)d_in[8];
  float* out = (float*)d_out;
  char* ws = (char*)d_ws;
  unsigned short* xb   = (unsigned short*)(ws + OFF_XB);
  unsigned short* w13b = (unsigned short*)(ws + OFF_W13);
  unsigned short* w2b  = (unsigned short*)(ws + OFF_W2);
  unsigned short* h    = (unsigned short*)(ws + OFF_H);
  int*   glist = (int*)(ws + OFF_GLIST);
  float* gw    = (float*)(ws + OFF_GW);
  int*   tidx  = (int*)(ws + OFF_TIDX);
  float* tw    = (float*)(ws + OFF_TW);
  int*   cnt   = (int*)(ws + OFF_CNT);
  int*   cnt2  = (int*)(ws + OFF_CNT2);
  int*   roff  = (int*)(ws + OFF_ROFF);
  int*   cpad  = (int*)(ws + OFF_CPAD);
  double* ent  = (double*)(ws + OFF_ENT);

  k_zero<<<(RCAP + 255) / 256, 256, 0, stream>>>(glist, gw, cnt, cnt2, ent);
  k_cvt_x<<<(TOK * DIMN / 4) / 256, 256, 0, stream>>>(x, xb);
  k_cvt_w13<<<dim3(2560, NSLOT), 256, 0, stream>>>(w1, w3, sw1, sw3, w13b);
  k_cvt_w2<<<dim3(DIMN, NSLOT), 256, 0, stream>>>(w2, sw2, w2b);
  k_gate<<<TOK / 4, 256, 0, stream>>>(x, emb, bias, tidx, tw, cnt, ent);
  k_offsets<<<1, 64, 0, stream>>>(cnt, roff, cpad, ent, out + (size_t)TOK * DIMN);
  k_scatter<<<TOK / 256, 256, 0, stream>>>(tidx, tw, roff, cnt2, glist, gw);
  k_gemm1<<<dim3(2 * HID / 128, TOK / 128, NSLOT), 256, 0, stream>>>(xb, w13b, h, glist, roff, cpad);
  k_gemm2s<<<dim3(DIMN / 128, TOK / 128), 256, 0, stream>>>(h, w2b, out);
  k_gemm2r<<<dim3(DIMN / 128, TOK / 128, NEXP), 256, 0, stream>>>(h, w2b, glist, gw, roff, cpad, out);
}

// Round 3
// 828.643 us; speedup vs baseline: 1.0403x; 1.0403x over previous
//
#include <hip/hip_runtime.h>
#include <math.h>

#define TOK 8192
#define DIMN 1024
#define HID 1280
#define NEXP 8
#define NSH 2
#define NSLOT 10
#define RCAP 17408          // 16384 + 8*128 max padding
#define RCAPG (RCAP + 256)  // glist/gw slack for 256-row gemm1 tiles
#define G1_NT (DIMN / 64)   // 16 K-tiles of 64

typedef short s16x8 __attribute__((ext_vector_type(8)));
typedef float f32x4 __attribute__((ext_vector_type(4)));

// f32 -> bf16 RNE
__device__ __forceinline__ unsigned short f2bf(float f) {
  unsigned u = __float_as_uint(f);
  u += 0x7fffu + ((u >> 16) & 1u);
  return (unsigned short)(u >> 16);
}

__device__ __forceinline__ void gl_lds16(const void* g, void* l) {
  typedef __attribute__((address_space(1))) const unsigned int guint;
  typedef __attribute__((address_space(3))) unsigned int luint;
  __builtin_amdgcn_global_load_lds((guint*)g, (luint*)l, 16, 0, 0);
}

// ---------------- init / zero ----------------
__global__ __launch_bounds__(256) void k_zero(int* __restrict__ glist, float* __restrict__ gw,
                                              int* __restrict__ cnt, int* __restrict__ cnt2,
                                              double* __restrict__ ent_acc) {
  int i = blockIdx.x * 256 + threadIdx.x;
  if (i < RCAPG) { glist[i] = 0; gw[i] = 0.0f; }
  if (i < NEXP) { cnt[i] = 0; cnt2[i] = 0; }
  if (i == 0) *ent_acc = 0.0;
}

// ---------------- converts ----------------
__global__ __launch_bounds__(256) void k_cvt_x(const float* __restrict__ x,
                                               unsigned short* __restrict__ xb) {
  int i = blockIdx.x * 256 + threadIdx.x;
  float4 v = ((const float4*)x)[i];
  ushort4 o;
  o.x = f2bf(v.x); o.y = f2bf(v.y); o.z = f2bf(v.z); o.w = f2bf(v.w);
  ((ushort4*)xb)[i] = o;
}

// w13b[slot][2560][1024]: row r: g=r>>5, which=(r>>4)&1, i=r&15 -> (which?w3:w1) row g*16+i
__global__ __launch_bounds__(256) void k_cvt_w13(const float* __restrict__ w1, const float* __restrict__ w3,
                                                 const float* __restrict__ sw1, const float* __restrict__ sw3,
                                                 unsigned short* __restrict__ w13b) {
  const int r = blockIdx.x;
  const int s = blockIdx.y;
  const int which = (r >> 4) & 1;
  const int srow = ((r >> 5) << 4) + (r & 15);
  const float* src;
  if (s < NSH) src = (which ? sw3 : sw1) + ((size_t)s * HID + srow) * DIMN;
  else         src = (which ? w3 : w1) + ((size_t)(s - NSH) * HID + srow) * DIMN;
  unsigned short* dst = w13b + ((size_t)s * 2560 + r) * DIMN;
  int c = threadIdx.x * 4;
  float4 v = *(const float4*)(src + c);
  ushort4 o;
  o.x = f2bf(v.x); o.y = f2bf(v.y); o.z = f2bf(v.z); o.w = f2bf(v.w);
  *(ushort4*)(dst + c) = o;
}

__global__ __launch_bounds__(256) void k_cvt_w2(const float* __restrict__ w2, const float* __restrict__ sw2,
                                                unsigned short* __restrict__ w2b) {
  const int d = blockIdx.x;
  const int s = blockIdx.y;
  const float* src = (s < NSH) ? sw2 + ((size_t)s * DIMN + d) * HID
                               : w2 + ((size_t)(s - NSH) * DIMN + d) * HID;
  unsigned short* dst = w2b + ((size_t)s * DIMN + d) * HID;
  for (int j = threadIdx.x; j < HID / 4; j += 256) {
    float4 v = ((const float4*)src)[j];
    ushort4 o;
    o.x = f2bf(v.x); o.y = f2bf(v.y); o.z = f2bf(v.z); o.w = f2bf(v.w);
    ((ushort4*)dst)[j] = o;
  }
}

// ---------------- gate (f32 semantics: sigmoid saturation + lowest-index tie-break) ----------------
__global__ __launch_bounds__(256) void k_gate(const float* __restrict__ x, const float* __restrict__ emb,
                                              const float* __restrict__ bias, int* __restrict__ tidx,
                                              float* __restrict__ tw, int* __restrict__ cnt,
                                              double* __restrict__ ent_acc) {
  const int lane = threadIdx.x & 63;
  const int wv = threadIdx.x >> 6;
  const int t = blockIdx.x * 4 + wv;
  const float* xr = x + (size_t)t * DIMN;
  float acc[NEXP];
#pragma unroll
  for (int e = 0; e < NEXP; ++e) acc[e] = 0.0f;
  for (int i = 0; i < DIMN / 64; ++i) {
    float xv = xr[lane + 64 * i];
#pragma unroll
    for (int e = 0; e < NEXP; ++e)
      acc[e] = fmaf(xv, emb[e * DIMN + lane + 64 * i], acc[e]);
  }
#pragma unroll
  for (int e = 0; e < NEXP; ++e) {
#pragma unroll
    for (int off = 32; off > 0; off >>= 1) acc[e] += __shfl_xor(acc[e], off);
  }
  __shared__ double ebuf[4];
  if (lane == 0) {
    float s[NEXP];
#pragma unroll
    for (int e = 0; e < NEXP; ++e) s[e] = 1.0f / (1.0f + expf(-acc[e])) + bias[e];
    int i0 = 0;
    for (int e = 1; e < NEXP; ++e) if (s[e] > s[i0]) i0 = e;
    int i1 = -1;
    for (int e = 0; e < NEXP; ++e) {
      if (e == i0) continue;
      if (i1 < 0 || s[e] > s[i1]) i1 = e;
    }
    float v0 = s[i0], v1 = s[i1];
    float inv = 1.0f / (v0 + v1);
    float w0 = v0 * inv, w1 = v1 * inv;
    tidx[2 * t] = i0; tidx[2 * t + 1] = i1;
    tw[2 * t] = w0; tw[2 * t + 1] = w1;
    atomicAdd(&cnt[i0], 1);
    atomicAdd(&cnt[i1], 1);
    ebuf[wv] = -(double)(w0 * logf(w0) + w1 * logf(w1));
  }
  __syncthreads();
  if (threadIdx.x == 0) atomicAdd(ent_acc, ebuf[0] + ebuf[1] + ebuf[2] + ebuf[3]);
}

// ---------------- offsets + tail finalize ----------------
__global__ void k_offsets(const int* __restrict__ cnt, int* __restrict__ roff, int* __restrict__ cpad,
                          const double* __restrict__ ent_acc, float* __restrict__ out_tail) {
  if (threadIdx.x == 0 && blockIdx.x == 0) {
    int off = 0;
    for (int e = 0; e < NEXP; ++e) {
      roff[e] = off;
      int cp = (cnt[e] + 127) & ~127;
      cpad[e] = cp;
      off += cp;
    }
    out_tail[0] = 0.0f;
    out_tail[1] = (float)(*ent_acc * (1.0 / TOK));
  }
}

// ---------------- scatter ----------------
__global__ __launch_bounds__(256) void k_scatter(const int* __restrict__ tidx, const float* __restrict__ tw,
                                                 const int* __restrict__ roff, int* __restrict__ cnt2,
                                                 int* __restrict__ glist, float* __restrict__ gw) {
  int t = blockIdx.x * 256 + threadIdx.x;
#pragma unroll
  for (int j = 0; j < 2; ++j) {
    int e = tidx[2 * t + j];
    int p = atomicAdd(&cnt2[e], 1);
    int g = roff[e] + p;
    glist[g] = t;
    gw[g] = tw[2 * t + j];
  }
}

// ---------------- GEMM1, 8-phase 256x256x64 (T2 swizzle + T3/T4 counted vmcnt + T5 setprio) ----
// h = silu(X@W1^T) * (X@W3^T); W1/W3 interleaved in 16-col groups inside w13b rows.
// LDS: 2 bufs x (A[256][64] + B[256][64]) bf16 = 128 KiB (dynamic).
// Swizzle: involution on byte bits 4-6 keyed by bits 8-10 (row bits 1-3); applied via
// pre-swizzled GLOBAL source on stage (gl_lds dest must be linear) and XOR on ds_read.
__global__ __launch_bounds__(512, 2) void k_gemm1_8ph(const unsigned short* __restrict__ xb,
                                                      const unsigned short* __restrict__ w13b,
                                                      unsigned short* __restrict__ h,
                                                      const int* __restrict__ glist,
                                                      const int* __restrict__ roff,
                                                      const int* __restrict__ cpad) {
  extern __shared__ __align__(16) char smem[];
  const int slot = blockIdx.z, yb = blockIdx.y, bx = blockIdx.x;
  const int tid = threadIdx.x;
  const int w = tid >> 6, lane = tid & 63;
  int hrow0, rowlim;
  int tokq[4];
  const int trbase = w * 8 + (lane >> 3);
  if (slot < NSH) {
    hrow0 = slot * TOK + yb * 256;
    rowlim = 256;
#pragma unroll
    for (int q = 0; q < 4; ++q) tokq[q] = yb * 256 + q * 64 + trbase;
  } else {
    const int e = slot - NSH;
    const int cp = cpad[e];
    if (yb * 256 >= cp) return;
    const int base = roff[e];
    hrow0 = 2 * TOK + base + yb * 256;
    rowlim = cp - yb * 256; if (rowlim > 256) rowlim = 256;
#pragma unroll
    for (int q = 0; q < 4; ++q) tokq[q] = glist[base + yb * 256 + q * 64 + trbase];
  }
  // stage source: per-lane in-row byte offset, pre-swizzled (dest byte bits 8-10 = lane4, lane5, w&1)
  const int srcoff = ((lane & 7) * 16) ^ (((lane >> 4) & 1) << 4) ^ (((lane >> 5) & 1) << 5) ^ ((w & 1) << 6);
  const char* aptr[4];
#pragma unroll
  for (int q = 0; q < 4; ++q) aptr[q] = (const char*)xb + (size_t)tokq[q] * 2048 + srcoff;
  const char* w13s = (const char*)w13b + (size_t)slot * 2560 * 2048;
  const int crow0 = (w >> 2) * 64 + (w & 3) * 8 + (lane >> 3);
  const char* bptr[2];
#pragma unroll
  for (int nq = 0; nq < 2; ++nq)
    bptr[nq] = w13s + (size_t)(bx * 256 + crow0 + nq * 32) * 2048 + srcoff;
  // wave-uniform LDS stage dest bases (within a buf)
  const int dA = (w * 8) * 128;                                   // + mh*8192 (+16384 second quarter)
  const int dB = 32768 + (((w >> 2) * 64 + (w & 3) * 8) * 128);   // + nq*4096 (+16384 second chunk)

#define STA(BB, MH, TT) do {                               \
    char* _d = smem + (BB) + dA + (MH) * 8192;             \
    gl_lds16(aptr[MH] + (TT) * 128, _d);                   \
    gl_lds16(aptr[(MH) + 2] + (TT) * 128, _d + 16384);     \
  } while (0)
#define STB(BB, NQ, TT) do {                               \
    char* _d = smem + (BB) + dB + (NQ) * 4096;             \
    gl_lds16(bptr[NQ] + (TT) * 128, _d);                   \
    gl_lds16(bptr[NQ] + 262144 + (TT) * 128, _d + 16384);  \
  } while (0)

  // fragment read bases; kswz = swizzle folded to lane-constant XOR (row bits 1-3 = lane bits 1-3)
  const int lr = lane & 15, lq = lane >> 4;
  const int kswz = (((lr >> 1) & 1) << 4) | (((lr >> 2) & 1) << 5) | (((lr >> 3) & 1) << 6);
  const int wm = w >> 2, wn = w & 3;  // 2(M) x 4(N) wave grid; per-wave out 128x64
  const int aoffb = (wm * 128 + lr) * 128 + lq * 16;
  const int boffb = 32768 + (wn * 64 + lr) * 128 + lq * 16;

#define RD_A(BB, MH) do {                                                                            \
    _Pragma("unroll")                                                                                \
    for (int mf = 0; mf < 4; ++mf)                                                                   \
      _Pragma("unroll")                                                                              \
      for (int ks = 0; ks < 2; ++ks)                                                                 \
        areg[mf][ks] = *(const s16x8*)(smem + (((BB) + aoffb + (MH) * 8192 + mf * 2048 + ks * 64) ^ kswz)); \
  } while (0)
#define RD_B(BB, NQ) do {                                                                            \
    _Pragma("unroll")                                                                                \
    for (int nf = 0; nf < 2; ++nf)                                                                   \
      _Pragma("unroll")                                                                              \
      for (int ks = 0; ks < 2; ++ks)                                                                 \
        breg[nf][ks] = *(const s16x8*)(smem + (((BB) + boffb + (NQ) * 4096 + nf * 2048 + ks * 64) ^ kswz)); \
  } while (0)
#define MFMA16(MH, NQ) do {                                                                          \
    __builtin_amdgcn_s_setprio(1);                                                                   \
    _Pragma("unroll")                                                                                \
    for (int mf = 0; mf < 4; ++mf)                                                                   \
      _Pragma("unroll")                                                                              \
      for (int nf = 0; nf < 2; ++nf)                                                                 \
        _Pragma("unroll")                                                                            \
        for (int ks = 0; ks < 2; ++ks)                                                               \
          acc[(MH) * 4 + mf][(NQ) * 2 + nf] = __builtin_amdgcn_mfma_f32_16x16x32_bf16(               \
              areg[mf][ks], breg[nf][ks], acc[(MH) * 4 + mf][(NQ) * 2 + nf], 0, 0, 0);               \
    __builtin_amdgcn_s_setprio(0);                                                                   \
  } while (0)
#define VMW(N) do { asm volatile("s_waitcnt vmcnt(" #N ")" ::: "memory"); __builtin_amdgcn_sched_barrier(0); } while (0)
#define BARR() __builtin_amdgcn_s_barrier()
#define LGKM0() do { asm volatile("s_waitcnt lgkmcnt(0)" ::: "memory"); __builtin_amdgcn_sched_barrier(0); } while (0)

  // prologue: tile0 full + tile1 (A-mh0, B-nq0); then wait+barrier so all waves' tile0 data visible
  STA(0, 0, 0); STB(0, 0, 0); STA(0, 1, 0); STB(0, 1, 0);
  STA(65536, 0, 1); STB(65536, 0, 1);
  VMW(4);
  BARR();

  f32x4 acc[8][4] = {};
  for (int j = 0; j < G1_NT; ++j) {
    const int bufb = (j & 1) << 16;
    const int bufo = bufb ^ 65536;
    const int t1 = (j + 1 < G1_NT) ? j + 1 : G1_NT - 1;  // clamped re-stage keeps vmcnt counts uniform
    const int t2 = (j + 2 < G1_NT) ? j + 2 : G1_NT - 1;
    s16x8 areg[4][2];
    s16x8 breg[2][2];
    // phase 0 (mh0,nq0): wait covers A-mh1(j)/B-nq1(j) (first read ph1/ph2, after this phase's barrier)
    VMW(4);
    RD_A(bufb, 0); RD_B(bufb, 0);
    STA(bufo, 1, t1);
    __builtin_amdgcn_sched_barrier(0);
    BARR(); LGKM0();
    MFMA16(0, 0);
    __builtin_amdgcn_sched_barrier(0);
    BARR();
    // phase 1 (mh0,nq1): A cached in regs
    RD_B(bufb, 1);
    STB(bufo, 1, t1);
    __builtin_amdgcn_sched_barrier(0);
    BARR(); LGKM0();
    MFMA16(0, 1);
    __builtin_amdgcn_sched_barrier(0);
    BARR();
    // phase 2 (mh1,nq0)
    RD_A(bufb, 1); RD_B(bufb, 0);
    STA(bufb, 0, t2);
    __builtin_amdgcn_sched_barrier(0);
    BARR(); LGKM0();
    MFMA16(1, 0);
    __builtin_amdgcn_sched_barrier(0);
    BARR();
    // phase 3 (mh1,nq1): wait covers A-mh0(j+1)/B-nq0(j+1) (read next tile ph0)
    VMW(6);
    RD_B(bufb, 1);
    STB(bufb, 0, t2);
    __builtin_amdgcn_sched_barrier(0);
    BARR(); LGKM0();
    MFMA16(1, 1);
    __builtin_amdgcn_sched_barrier(0);
    BARR();
  }
#undef STA
#undef STB
#undef RD_A
#undef RD_B
#undef MFMA16

  asm volatile("s_waitcnt vmcnt(0)" ::: "memory");
  // epilogue: silu(w1col)*w3col -> h (bf16); C frag: col=lane&15, row=lq*4+reg
#pragma unroll
  for (int m = 0; m < 8; ++m) {
    const int lrow0 = wm * 128 + (m >> 2) * 64 + (m & 3) * 16 + lq * 4;
#pragma unroll
    for (int p = 0; p < 2; ++p) {
      f32x4 a1 = acc[m][2 * p];
      f32x4 a3 = acc[m][2 * p + 1];
      const int hc = (bx * 8 + wn * 2 + p) * 16 + lr;
#pragma unroll
      for (int r = 0; r < 4; ++r) {
        const int lrow = lrow0 + r;
        if (lrow < rowlim) {
          float u = a1[r];
          float hv = (u / (1.f + __expf(-u))) * a3[r];
          h[(size_t)(hrow0 + lrow) * HID + hc] = f2bf(hv);
        }
      }
    }
  }
#undef VMW
#undef BARR
#undef LGKM0
}

// ---------------- GEMM2 shared: out = 0.5*(h0@W2_0^T + h1@W2_1^T), K=2560 concat ----------------
__global__ __launch_bounds__(256) void k_gemm2s(const unsigned short* __restrict__ h,
                                                const unsigned short* __restrict__ w2b,
                                                float* __restrict__ out) {
  __shared__ __align__(16) unsigned short As[2][4096];
  __shared__ __align__(16) unsigned short Bs[2][4096];
  const int yb = blockIdx.y, bx = blockIdx.x, tid = threadIdx.x;
  const int wv = tid >> 6, lane = tid & 63, wm = wv >> 1, wn = wv & 1;
  const int kc = (tid & 3) * 8;
  const int tr = yb * 128 + (tid >> 2);
  const int nr = bx * 128 + (tid >> 2);
  const unsigned short* a0s0 = h + (size_t)tr * HID + kc;
  const unsigned short* a1s0 = h + (size_t)(tr + 64) * HID + kc;
  const unsigned short* a0s1 = h + (size_t)(TOK + tr) * HID + kc;
  const unsigned short* a1s1 = h + (size_t)(TOK + tr + 64) * HID + kc;
  const unsigned short* b0s0 = w2b + (size_t)nr * HID + kc;
  const unsigned short* b1s0 = b0s0 + (size_t)64 * HID;
  const unsigned short* b0s1 = w2b + (size_t)(DIMN + nr) * HID + kc;
  const unsigned short* b1s1 = b0s1 + (size_t)64 * HID;
  f32x4 acc[4][4] = {};
#define STAGE2S(buf, kt) do {                                             \
    int _k0 = (kt) * 32;                                                  \
    int _k = (_k0 < HID) ? _k0 : _k0 - HID;                               \
    const unsigned short* _a0 = (_k0 < HID) ? a0s0 : a0s1;                \
    const unsigned short* _a1 = (_k0 < HID) ? a1s0 : a1s1;                \
    const unsigned short* _b0 = (_k0 < HID) ? b0s0 : b0s1;                \
    const unsigned short* _b1 = (_k0 < HID) ? b1s0 : b1s1;                \
    gl_lds16(_a0 + _k, &As[buf][wv * 512]);                               \
    gl_lds16(_a1 + _k, &As[buf][2048 + wv * 512]);                        \
    gl_lds16(_b0 + _k, &Bs[buf][wv * 512]);                               \
    gl_lds16(_b1 + _k, &Bs[buf][2048 + wv * 512]);                        \
  } while (0)
  STAGE2S(0, 0);
  const int aoff = (wm * 64 + (lane & 15)) * 32 + (lane >> 4) * 8;
  const int boff = (wn * 64 + (lane & 15)) * 32 + (lane >> 4) * 8;
  int cur = 0;
  for (int kt = 0; kt < 2 * HID / 32; ++kt) {
    __syncthreads();
    if (kt + 1 < 2 * HID / 32) STAGE2S(cur ^ 1, kt + 1);
    const unsigned short* Ab = &As[cur][aoff];
    const unsigned short* Bb = &Bs[cur][boff];
    s16x8 af[4], bfv[4];
#pragma unroll
    for (int f = 0; f < 4; ++f) af[f] = *(const s16x8*)(Ab + f * 512);
#pragma unroll
    for (int f = 0; f < 4; ++f) bfv[f] = *(const s16x8*)(Bb + f * 512);
#pragma unroll
    for (int i = 0; i < 4; ++i)
#pragma unroll
      for (int j = 0; j < 4; ++j)
        acc[i][j] = __builtin_amdgcn_mfma_f32_16x16x32_bf16(af[i], bfv[j], acc[i][j], 0, 0, 0);
    cur ^= 1;
  }
#undef STAGE2S
  const int lr = lane & 15, lq = lane >> 4;
#pragma unroll
  for (int mf = 0; mf < 4; ++mf) {
    const int t = yb * 128 + wm * 64 + mf * 16 + lq * 4;
#pragma unroll
    for (int nf = 0; nf < 4; ++nf) {
      const int col = bx * 128 + wn * 64 + nf * 16 + lr;
#pragma unroll
      for (int r = 0; r < 4; ++r)
        out[(size_t)(t + r) * DIMN + col] = 0.5f * acc[mf][nf][r];
    }
  }
}

// ---------------- GEMM2 routed: out[tok] += wgt * (h_e @ W2_e^T) ----------------
__global__ __launch_bounds__(256) void k_gemm2r(const unsigned short* __restrict__ h,
                                                const unsigned short* __restrict__ w2b,
                                                const int* __restrict__ glist,
                                                const float* __restrict__ gw,
                                                const int* __restrict__ roff,
                                                const int* __restrict__ cpad,
                                                float* __restrict__ out) {
  __shared__ __align__(16) unsigned short As[2][4096];
  __shared__ __align__(16) unsigned short Bs[2][4096];
  const int e = blockIdx.z, yb = blockIdx.y, bx = blockIdx.x, tid = threadIdx.x;
  if (yb * 128 >= cpad[e]) return;
  const int base = roff[e];
  const unsigned short* hA = h + (size_t)(2 * TOK + base) * HID;
  const unsigned short* w2s = w2b + (size_t)(NSH + e) * DIMN * HID;
  const int wv = tid >> 6, lane = tid & 63, wm = wv >> 1, wn = wv & 1;
  const int kc = (tid & 3) * 8;
  const unsigned short* ap0 = hA + ((size_t)yb * 128 + (tid >> 2)) * HID + kc;
  const unsigned short* ap1 = ap0 + (size_t)64 * HID;
  const unsigned short* bp0 = w2s + ((size_t)bx * 128 + (tid >> 2)) * HID + kc;
  const unsigned short* bp1 = bp0 + (size_t)64 * HID;
  f32x4 acc[4][4] = {};
#define STAGE2R(buf, kt) do {                                 \
    int _ko = (kt) * 32;                                      \
    gl_lds16(ap0 + _ko, &As[buf][wv * 512]);                  \
    gl_lds16(ap1 + _ko, &As[buf][2048 + wv * 512]);           \
    gl_lds16(bp0 + _ko, &Bs[buf][wv * 512]);                  \
    gl_lds16(bp1 + _ko, &Bs[buf][2048 + wv * 512]);           \
  } while (0)
  STAGE2R(0, 0);
  const int aoff = (wm * 64 + (lane & 15)) * 32 + (lane >> 4) * 8;
  const int boff = (wn * 64 + (lane & 15)) * 32 + (lane >> 4) * 8;
  int cur = 0;
  for (int kt = 0; kt < HID / 32; ++kt) {
    __syncthreads();
    if (kt + 1 < HID / 32) STAGE2R(cur ^ 1, kt + 1);
    const unsigned short* Ab = &As[cur][aoff];
    const unsigned short* Bb = &Bs[cur][boff];
    s16x8 af[4], bfv[4];
#pragma unroll
    for (int f = 0; f < 4; ++f) af[f] = *(const s16x8*)(Ab + f * 512);
#pragma unroll
    for (int f = 0; f < 4; ++f) bfv[f] = *(const s16x8*)(Bb + f * 512);
#pragma unroll
    for (int i = 0; i < 4; ++i)
#pragma unroll
      for (int j = 0; j < 4; ++j)
        acc[i][j] = __builtin_amdgcn_mfma_f32_16x16x32_bf16(af[i], bfv[j], acc[i][j], 0, 0, 0);
    cur ^= 1;
  }
#undef STAGE2R
  const int lr = lane & 15, lq = lane >> 4;
#pragma unroll
  for (int mf = 0; mf < 4; ++mf) {
    const int lrow = yb * 128 + wm * 64 + mf * 16 + lq * 4;
#pragma unroll
    for (int r = 0; r < 4; ++r) {
      const int g = base + lrow + r;
      const int t = glist[g];
      const float wgt = gw[g];
#pragma unroll
      for (int nf = 0; nf < 4; ++nf) {
        const int col = bx * 128 + wn * 64 + nf * 16 + lr;
        atomicAdd(&out[(size_t)t * DIMN + col], wgt * acc[mf][nf][r]);
      }
    }
  }
}

// ---------------- ws layout ----------------
static const size_t OFF_XB    = 0;
static const size_t OFF_W13   = OFF_XB + (size_t)TOK * DIMN * 2;
static const size_t OFF_W2    = OFF_W13 + (size_t)NSLOT * 2560 * DIMN * 2;
static const size_t OFF_H     = OFF_W2 + (size_t)NSLOT * DIMN * HID * 2;
static const size_t OFF_GLIST = OFF_H + (size_t)(2 * TOK + RCAP) * HID * 2;
static const size_t OFF_GW    = OFF_GLIST + (size_t)RCAPG * 4;
static const size_t OFF_TIDX  = OFF_GW + (size_t)RCAPG * 4;
static const size_t OFF_TW    = OFF_TIDX + (size_t)TOK * 2 * 4;
static const size_t OFF_CNT   = OFF_TW + (size_t)TOK * 2 * 4;
static const size_t OFF_CNT2  = OFF_CNT + 32;
static const size_t OFF_ROFF  = OFF_CNT2 + 32;
static const size_t OFF_CPAD  = OFF_ROFF + 32;
static const size_t OFF_ENT   = OFF_CPAD + 32;

extern "C" void kernel_launch(void* const* d_in, const int* in_sizes, int n_in,
                              void* d_out, int out_size, void* d_ws, size_t ws_size,
                              hipStream_t stream) {
  const float* x    = (const float*)d_in[0];
  const float* emb  = (const float*)d_in[1];
  const float* bias = (const float*)d_in[2];
  const float* w1   = (const float*)d_in[3];
  const float* w2   = (const float*)d_in[4];
  const float* w3   = (const float*)d_in[5];
  const float* sw1  = (const float*)d_in[6];
  const float* sw2  = (const float*)d_in[7];
  const float* sw3  = (const float*)d_in[8];
  float* out = (float*)d_out;
  char* ws = (char*)d_ws;
  unsigned short* xb   = (unsigned short*)(ws + OFF_XB);
  unsigned short* w13b = (unsigned short*)(ws + OFF_W13);
  unsigned short* w2b  = (unsigned short*)(ws + OFF_W2);
  unsigned short* h    = (unsigned short*)(ws + OFF_H);
  int*   glist = (int*)(ws + OFF_GLIST);
  float* gw    = (float*)(ws + OFF_GW);
  int*   tidx  = (int*)(ws + OFF_TIDX);
  float* tw    = (float*)(ws + OFF_TW);
  int*   cnt   = (int*)(ws + OFF_CNT);
  int*   cnt2  = (int*)(ws + OFF_CNT2);
  int*   roff  = (int*)(ws + OFF_ROFF);
  int*   cpad  = (int*)(ws + OFF_CPAD);
  double* ent  = (double*)(ws + OFF_ENT);

  hipFuncSetAttribute((const void*)k_gemm1_8ph, hipFuncAttributeMaxDynamicSharedMemorySize, 131072);

  k_zero<<<(RCAPG + 255) / 256, 256, 0, stream>>>(glist, gw, cnt, cnt2, ent);
  k_cvt_x<<<(TOK * DIMN / 4) / 256, 256, 0, stream>>>(x, xb);
  k_cvt_w13<<<dim3(2560, NSLOT), 256, 0, stream>>>(w1, w3, sw1, sw3, w13b);
  k_cvt_w2<<<dim3(DIMN, NSLOT), 256, 0, stream>>>(w2, sw2, w2b);
  k_gate<<<TOK / 4, 256, 0, stream>>>(x, emb, bias, tidx, tw, cnt, ent);
  k_offsets<<<1, 64, 0, stream>>>(cnt, roff, cpad, ent, out + (size_t)TOK * DIMN);
  k_scatter<<<TOK / 256, 256, 0, stream>>>(tidx, tw, roff, cnt2, glist, gw);
  k_gemm1_8ph<<<dim3(2560 / 256, TOK / 256, NSLOT), 512, 131072, stream>>>(xb, w13b, h, glist, roff, cpad);
  k_gemm2s<<<dim3(DIMN / 128, TOK / 128), 256, 0, stream>>>(h, w2b, out);
  k_gemm2r<<<dim3(DIMN / 128, TOK / 128, NEXP), 256, 0, stream>>>(h, w2b, glist, gw, roff, cpad, out);
}

// Round 4
// 817.986 us; speedup vs baseline: 1.0538x; 1.0130x over previous
//
#include <hip/hip_runtime.h>
#include <math.h>

#define TOK 8192
#define DIMN 1024
#define HID 1280
#define NEXP 8
#define NSH 2
#define NSLOT 10
#define RCAP 17408          // 16384 + 8*128 max padding
#define RCAPG (RCAP + 256)  // glist/gw slack for 256-row gemm1 tiles
#define G1_NT (DIMN / 64)   // 16 K-tiles of 64

typedef short s16x8 __attribute__((ext_vector_type(8)));
typedef float f32x4 __attribute__((ext_vector_type(4)));

// f32 -> bf16 RNE
__device__ __forceinline__ unsigned short f2bf(float f) {
  unsigned u = __float_as_uint(f);
  u += 0x7fffu + ((u >> 16) & 1u);
  return (unsigned short)(u >> 16);
}

__device__ __forceinline__ void gl_lds16(const void* g, void* l) {
  typedef __attribute__((address_space(1))) const unsigned int guint;
  typedef __attribute__((address_space(3))) unsigned int luint;
  __builtin_amdgcn_global_load_lds((guint*)g, (luint*)l, 16, 0, 0);
}

// ---------------- init / zero ----------------
__global__ __launch_bounds__(256) void k_zero(int* __restrict__ glist, float* __restrict__ gw,
                                              int* __restrict__ cnt, int* __restrict__ cnt2,
                                              double* __restrict__ ent_acc) {
  int i = blockIdx.x * 256 + threadIdx.x;
  if (i < RCAPG) { glist[i] = 0; gw[i] = 0.0f; }
  if (i < NEXP) { cnt[i] = 0; cnt2[i] = 0; }
  if (i == 0) *ent_acc = 0.0;
}

// ---------------- converts ----------------
__global__ __launch_bounds__(256) void k_cvt_x(const float* __restrict__ x,
                                               unsigned short* __restrict__ xb) {
  int i = blockIdx.x * 256 + threadIdx.x;
  float4 v = ((const float4*)x)[i];
  ushort4 o;
  o.x = f2bf(v.x); o.y = f2bf(v.y); o.z = f2bf(v.z); o.w = f2bf(v.w);
  ((ushort4*)xb)[i] = o;
}

// w13b[slot][2560][1024]: row r: g=r>>5, which=(r>>4)&1, i=r&15 -> (which?w3:w1) row g*16+i
__global__ __launch_bounds__(256) void k_cvt_w13(const float* __restrict__ w1, const float* __restrict__ w3,
                                                 const float* __restrict__ sw1, const float* __restrict__ sw3,
                                                 unsigned short* __restrict__ w13b) {
  const int r = blockIdx.x;
  const int s = blockIdx.y;
  const int which = (r >> 4) & 1;
  const int srow = ((r >> 5) << 4) + (r & 15);
  const float* src;
  if (s < NSH) src = (which ? sw3 : sw1) + ((size_t)s * HID + srow) * DIMN;
  else         src = (which ? w3 : w1) + ((size_t)(s - NSH) * HID + srow) * DIMN;
  unsigned short* dst = w13b + ((size_t)s * 2560 + r) * DIMN;
  int c = threadIdx.x * 4;
  float4 v = *(const float4*)(src + c);
  ushort4 o;
  o.x = f2bf(v.x); o.y = f2bf(v.y); o.z = f2bf(v.z); o.w = f2bf(v.w);
  *(ushort4*)(dst + c) = o;
}

__global__ __launch_bounds__(256) void k_cvt_w2(const float* __restrict__ w2, const float* __restrict__ sw2,
                                                unsigned short* __restrict__ w2b) {
  const int d = blockIdx.x;
  const int s = blockIdx.y;
  const float* src = (s < NSH) ? sw2 + ((size_t)s * DIMN + d) * HID
                               : w2 + ((size_t)(s - NSH) * DIMN + d) * HID;
  unsigned short* dst = w2b + ((size_t)s * DIMN + d) * HID;
  for (int j = threadIdx.x; j < HID / 4; j += 256) {
    float4 v = ((const float4*)src)[j];
    ushort4 o;
    o.x = f2bf(v.x); o.y = f2bf(v.y); o.z = f2bf(v.z); o.w = f2bf(v.w);
    ((ushort4*)dst)[j] = o;
  }
}

// ---------------- gate (f32 semantics: sigmoid saturation + lowest-index tie-break) ----------------
__global__ __launch_bounds__(256) void k_gate(const float* __restrict__ x, const float* __restrict__ emb,
                                              const float* __restrict__ bias, int* __restrict__ tidx,
                                              float* __restrict__ tw, int* __restrict__ cnt,
                                              double* __restrict__ ent_acc) {
  const int lane = threadIdx.x & 63;
  const int wv = threadIdx.x >> 6;
  const int t = blockIdx.x * 4 + wv;
  const float* xr = x + (size_t)t * DIMN;
  float acc[NEXP];
#pragma unroll
  for (int e = 0; e < NEXP; ++e) acc[e] = 0.0f;
  for (int i = 0; i < DIMN / 64; ++i) {
    float xv = xr[lane + 64 * i];
#pragma unroll
    for (int e = 0; e < NEXP; ++e)
      acc[e] = fmaf(xv, emb[e * DIMN + lane + 64 * i], acc[e]);
  }
#pragma unroll
  for (int e = 0; e < NEXP; ++e) {
#pragma unroll
    for (int off = 32; off > 0; off >>= 1) acc[e] += __shfl_xor(acc[e], off);
  }
  __shared__ double ebuf[4];
  if (lane == 0) {
    float s[NEXP];
#pragma unroll
    for (int e = 0; e < NEXP; ++e) s[e] = 1.0f / (1.0f + expf(-acc[e])) + bias[e];
    int i0 = 0;
    for (int e = 1; e < NEXP; ++e) if (s[e] > s[i0]) i0 = e;
    int i1 = -1;
    for (int e = 0; e < NEXP; ++e) {
      if (e == i0) continue;
      if (i1 < 0 || s[e] > s[i1]) i1 = e;
    }
    float v0 = s[i0], v1 = s[i1];
    float inv = 1.0f / (v0 + v1);
    float w0 = v0 * inv, w1 = v1 * inv;
    tidx[2 * t] = i0; tidx[2 * t + 1] = i1;
    tw[2 * t] = w0; tw[2 * t + 1] = w1;
    atomicAdd(&cnt[i0], 1);
    atomicAdd(&cnt[i1], 1);
    ebuf[wv] = -(double)(w0 * logf(w0) + w1 * logf(w1));
  }
  __syncthreads();
  if (threadIdx.x == 0) atomicAdd(ent_acc, ebuf[0] + ebuf[1] + ebuf[2] + ebuf[3]);
}

// ---------------- offsets + tail finalize ----------------
__global__ void k_offsets(const int* __restrict__ cnt, int* __restrict__ roff, int* __restrict__ cpad,
                          const double* __restrict__ ent_acc, float* __restrict__ out_tail) {
  if (threadIdx.x == 0 && blockIdx.x == 0) {
    int off = 0;
    for (int e = 0; e < NEXP; ++e) {
      roff[e] = off;
      int cp = (cnt[e] + 127) & ~127;
      cpad[e] = cp;
      off += cp;
    }
    out_tail[0] = 0.0f;
    out_tail[1] = (float)(*ent_acc * (1.0 / TOK));
  }
}

// ---------------- scatter ----------------
__global__ __launch_bounds__(256) void k_scatter(const int* __restrict__ tidx, const float* __restrict__ tw,
                                                 const int* __restrict__ roff, int* __restrict__ cnt2,
                                                 int* __restrict__ glist, float* __restrict__ gw) {
  int t = blockIdx.x * 256 + threadIdx.x;
#pragma unroll
  for (int j = 0; j < 2; ++j) {
    int e = tidx[2 * t + j];
    int p = atomicAdd(&cnt2[e], 1);
    int g = roff[e] + p;
    glist[g] = t;
    gw[g] = tw[2 * t + j];
  }
}

// ---------------- GEMM1, 8-phase 256x256x64 ----------------
// Changes vs round 3: (1) sched_barrier(0) ONLY after lgkmcnt(0) (rule #18); all
// other pins removed (m141: order-pinning defeats compiler scheduling).
// (2) minimal LDS reads: 24 ds_read_b128/wave/K-tile — phase order
// (0,0)->(0,1)->(1,1)->(1,0) with BOTH B halves register-cached; ph3 has zero reads.
// vmcnt schedule: prologue 12 loads -> vmcnt(4); steady: vmcnt(4)@ph0, vmcnt(8)@ph3.
__global__ __launch_bounds__(512, 2) void k_gemm1_8ph(const unsigned short* __restrict__ xb,
                                                      const unsigned short* __restrict__ w13b,
                                                      unsigned short* __restrict__ h,
                                                      const int* __restrict__ glist,
                                                      const int* __restrict__ roff,
                                                      const int* __restrict__ cpad) {
  extern __shared__ __align__(16) char smem[];
  const int slot = blockIdx.z, yb = blockIdx.y, bx = blockIdx.x;
  const int tid = threadIdx.x;
  const int w = tid >> 6, lane = tid & 63;
  int hrow0, rowlim;
  int tokq[4];
  const int trbase = w * 8 + (lane >> 3);
  if (slot < NSH) {
    hrow0 = slot * TOK + yb * 256;
    rowlim = 256;
#pragma unroll
    for (int q = 0; q < 4; ++q) tokq[q] = yb * 256 + q * 64 + trbase;
  } else {
    const int e = slot - NSH;
    const int cp = cpad[e];
    if (yb * 256 >= cp) return;
    const int base = roff[e];
    hrow0 = 2 * TOK + base + yb * 256;
    rowlim = cp - yb * 256; if (rowlim > 256) rowlim = 256;
#pragma unroll
    for (int q = 0; q < 4; ++q) tokq[q] = glist[base + yb * 256 + q * 64 + trbase];
  }
  // stage source: per-lane in-row byte offset, pre-swizzled (dest byte bits 8-10 = lane4, lane5, w&1)
  const int srcoff = ((lane & 7) * 16) ^ (((lane >> 4) & 1) << 4) ^ (((lane >> 5) & 1) << 5) ^ ((w & 1) << 6);
  const char* aptr[4];
#pragma unroll
  for (int q = 0; q < 4; ++q) aptr[q] = (const char*)xb + (size_t)tokq[q] * 2048 + srcoff;
  const char* w13s = (const char*)w13b + (size_t)slot * 2560 * 2048;
  const int crow0 = (w >> 2) * 64 + (w & 3) * 8 + (lane >> 3);
  const char* bptr[2];
#pragma unroll
  for (int nq = 0; nq < 2; ++nq)
    bptr[nq] = w13s + (size_t)(bx * 256 + crow0 + nq * 32) * 2048 + srcoff;
  // wave-uniform LDS stage dest bases (within a buf)
  const int dA = (w * 8) * 128;
  const int dB = 32768 + (((w >> 2) * 64 + (w & 3) * 8) * 128);

#define STA(BB, MH, TT) do {                               \
    char* _d = smem + (BB) + dA + (MH) * 8192;             \
    gl_lds16(aptr[MH] + (TT) * 128, _d);                   \
    gl_lds16(aptr[(MH) + 2] + (TT) * 128, _d + 16384);     \
  } while (0)
#define STB(BB, NQ, TT) do {                               \
    char* _d = smem + (BB) + dB + (NQ) * 4096;             \
    gl_lds16(bptr[NQ] + (TT) * 128, _d);                   \
    gl_lds16(bptr[NQ] + 262144 + (TT) * 128, _d + 16384);  \
  } while (0)

  // fragment read bases; kswz = swizzle folded to lane-constant XOR (row bits 1-3 = lane bits 1-3)
  const int lr = lane & 15, lq = lane >> 4;
  const int kswz = (((lr >> 1) & 1) << 4) | (((lr >> 2) & 1) << 5) | (((lr >> 3) & 1) << 6);
  const int wm = w >> 2, wn = w & 3;  // 2(M) x 4(N) wave grid; per-wave out 128x64
  const int aoffb = (wm * 128 + lr) * 128 + lq * 16;
  const int boffb = 32768 + (wn * 64 + lr) * 128 + lq * 16;

#define RD_A(BB, MH) do {                                                                            \
    _Pragma("unroll")                                                                                \
    for (int mf = 0; mf < 4; ++mf)                                                                   \
      _Pragma("unroll")                                                                              \
      for (int ks = 0; ks < 2; ++ks)                                                                 \
        areg[mf][ks] = *(const s16x8*)(smem + (((BB) + aoffb + (MH) * 8192 + mf * 2048 + ks * 64) ^ kswz)); \
  } while (0)
#define RD_B(BB, NQ, RG) do {                                                                        \
    _Pragma("unroll")                                                                                \
    for (int nf = 0; nf < 2; ++nf)                                                                   \
      _Pragma("unroll")                                                                              \
      for (int ks = 0; ks < 2; ++ks)                                                                 \
        RG[nf][ks] = *(const s16x8*)(smem + (((BB) + boffb + (NQ) * 4096 + nf * 2048 + ks * 64) ^ kswz)); \
  } while (0)
#define MFMA16(MH, RG, NQ) do {                                                                      \
    __builtin_amdgcn_s_setprio(1);                                                                   \
    _Pragma("unroll")                                                                                \
    for (int mf = 0; mf < 4; ++mf)                                                                   \
      _Pragma("unroll")                                                                              \
      for (int nf = 0; nf < 2; ++nf)                                                                 \
        _Pragma("unroll")                                                                            \
        for (int ks = 0; ks < 2; ++ks)                                                               \
          acc[(MH) * 4 + mf][(NQ) * 2 + nf] = __builtin_amdgcn_mfma_f32_16x16x32_bf16(               \
              areg[mf][ks], RG[nf][ks], acc[(MH) * 4 + mf][(NQ) * 2 + nf], 0, 0, 0);                 \
    __builtin_amdgcn_s_setprio(0);                                                                   \
  } while (0)
#define VMW(N) asm volatile("s_waitcnt vmcnt(" #N ")" ::: "memory")
#define BARR() __builtin_amdgcn_s_barrier()
#define LGKM0() do { asm volatile("s_waitcnt lgkmcnt(0)" ::: "memory"); __builtin_amdgcn_sched_barrier(0); } while (0)

  // prologue: tile0 full + tile1 (A0, B0); 12 loads -> vmcnt(4) completes tile0
  STA(0, 0, 0); STB(0, 0, 0); STA(0, 1, 0); STB(0, 1, 0);
  STA(65536, 0, 1); STB(65536, 0, 1);
  VMW(4);
  BARR();

  f32x4 acc[8][4] = {};
  for (int j = 0; j < G1_NT; ++j) {
    const int bufb = (j & 1) << 16;
    const int bufo = bufb ^ 65536;
    const int t1 = (j + 1 < G1_NT) ? j + 1 : G1_NT - 1;  // clamped re-stage keeps vmcnt counts uniform
    const int t2 = (j + 2 < G1_NT) ? j + 2 : G1_NT - 1;
    s16x8 areg[4][2];
    s16x8 breg0[2][2], breg1[2][2];
    // ph0 (mh0,nq0): vmcnt(4) completes A1(cur)/B1(cur) before ph1/ph2 read them
    VMW(4);
    RD_A(bufb, 0);
    RD_B(bufb, 0, breg0);
    STA(bufo, 1, t1);
    BARR(); LGKM0();
    MFMA16(0, breg0, 0);
    BARR();
    // ph1 (mh0,nq1)
    RD_B(bufb, 1, breg1);
    STB(bufo, 1, t1);
    BARR(); LGKM0();
    MFMA16(0, breg1, 1);
    BARR();
    // ph2 (mh1,nq1): A half swapped; breg1 reused from ph1
    RD_A(bufb, 1);
    STA(bufb, 0, t2);
    BARR(); LGKM0();
    MFMA16(1, breg1, 1);
    BARR();
    // ph3 (mh1,nq0): zero ds_reads (breg0 cached since ph0); counted vmcnt before tile boundary
    STB(bufb, 0, t2);
    BARR();
    MFMA16(1, breg0, 0);
    VMW(8);
    BARR();
  }
#undef STA
#undef STB
#undef RD_A
#undef RD_B
#undef MFMA16

  asm volatile("s_waitcnt vmcnt(0)" ::: "memory");
  // epilogue: silu(w1col)*w3col -> h (bf16); C frag: col=lane&15, row=lq*4+reg
#pragma unroll
  for (int m = 0; m < 8; ++m) {
    const int lrow0 = wm * 128 + (m >> 2) * 64 + (m & 3) * 16 + lq * 4;
#pragma unroll
    for (int p = 0; p < 2; ++p) {
      f32x4 a1 = acc[m][2 * p];
      f32x4 a3 = acc[m][2 * p + 1];
      const int hc = (bx * 8 + wn * 2 + p) * 16 + lr;
#pragma unroll
      for (int r = 0; r < 4; ++r) {
        const int lrow = lrow0 + r;
        if (lrow < rowlim) {
          float u = a1[r];
          float hv = (u / (1.f + __expf(-u))) * a3[r];
          h[(size_t)(hrow0 + lrow) * HID + hc] = f2bf(hv);
        }
      }
    }
  }
#undef VMW
#undef BARR
#undef LGKM0
}

// ---------------- GEMM2 shared: out = 0.5*(h0@W2_0^T + h1@W2_1^T), K=2560 concat ----------------
__global__ __launch_bounds__(256) void k_gemm2s(const unsigned short* __restrict__ h,
                                                const unsigned short* __restrict__ w2b,
                                                float* __restrict__ out) {
  __shared__ __align__(16) unsigned short As[2][4096];
  __shared__ __align__(16) unsigned short Bs[2][4096];
  const int yb = blockIdx.y, bx = blockIdx.x, tid = threadIdx.x;
  const int wv = tid >> 6, lane = tid & 63, wm = wv >> 1, wn = wv & 1;
  const int kc = (tid & 3) * 8;
  const int tr = yb * 128 + (tid >> 2);
  const int nr = bx * 128 + (tid >> 2);
  const unsigned short* a0s0 = h + (size_t)tr * HID + kc;
  const unsigned short* a1s0 = h + (size_t)(tr + 64) * HID + kc;
  const unsigned short* a0s1 = h + (size_t)(TOK + tr) * HID + kc;
  const unsigned short* a1s1 = h + (size_t)(TOK + tr + 64) * HID + kc;
  const unsigned short* b0s0 = w2b + (size_t)nr * HID + kc;
  const unsigned short* b1s0 = b0s0 + (size_t)64 * HID;
  const unsigned short* b0s1 = w2b + (size_t)(DIMN + nr) * HID + kc;
  const unsigned short* b1s1 = b0s1 + (size_t)64 * HID;
  f32x4 acc[4][4] = {};
#define STAGE2S(buf, kt) do {                                             \
    int _k0 = (kt) * 32;                                                  \
    int _k = (_k0 < HID) ? _k0 : _k0 - HID;                               \
    const unsigned short* _a0 = (_k0 < HID) ? a0s0 : a0s1;                \
    const unsigned short* _a1 = (_k0 < HID) ? a1s0 : a1s1;                \
    const unsigned short* _b0 = (_k0 < HID) ? b0s0 : b0s1;                \
    const unsigned short* _b1 = (_k0 < HID) ? b1s0 : b1s1;                \
    gl_lds16(_a0 + _k, &As[buf][wv * 512]);                               \
    gl_lds16(_a1 + _k, &As[buf][2048 + wv * 512]);                        \
    gl_lds16(_b0 + _k, &Bs[buf][wv * 512]);                               \
    gl_lds16(_b1 + _k, &Bs[buf][2048 + wv * 512]);                        \
  } while (0)
  STAGE2S(0, 0);
  const int aoff = (wm * 64 + (lane & 15)) * 32 + (lane >> 4) * 8;
  const int boff = (wn * 64 + (lane & 15)) * 32 + (lane >> 4) * 8;
  int cur = 0;
  for (int kt = 0; kt < 2 * HID / 32; ++kt) {
    __syncthreads();
    if (kt + 1 < 2 * HID / 32) STAGE2S(cur ^ 1, kt + 1);
    const unsigned short* Ab = &As[cur][aoff];
    const unsigned short* Bb = &Bs[cur][boff];
    s16x8 af[4], bfv[4];
#pragma unroll
    for (int f = 0; f < 4; ++f) af[f] = *(const s16x8*)(Ab + f * 512);
#pragma unroll
    for (int f = 0; f < 4; ++f) bfv[f] = *(const s16x8*)(Bb + f * 512);
#pragma unroll
    for (int i = 0; i < 4; ++i)
#pragma unroll
      for (int j = 0; j < 4; ++j)
        acc[i][j] = __builtin_amdgcn_mfma_f32_16x16x32_bf16(af[i], bfv[j], acc[i][j], 0, 0, 0);
    cur ^= 1;
  }
#undef STAGE2S
  const int lr = lane & 15, lq = lane >> 4;
#pragma unroll
  for (int mf = 0; mf < 4; ++mf) {
    const int t = yb * 128 + wm * 64 + mf * 16 + lq * 4;
#pragma unroll
    for (int nf = 0; nf < 4; ++nf) {
      const int col = bx * 128 + wn * 64 + nf * 16 + lr;
#pragma unroll
      for (int r = 0; r < 4; ++r)
        out[(size_t)(t + r) * DIMN + col] = 0.5f * acc[mf][nf][r];
    }
  }
}

// ---------------- GEMM2 routed: out[tok] += wgt * (h_e @ W2_e^T) ----------------
__global__ __launch_bounds__(256) void k_gemm2r(const unsigned short* __restrict__ h,
                                                const unsigned short* __restrict__ w2b,
                                                const int* __restrict__ glist,
                                                const float* __restrict__ gw,
                                                const int* __restrict__ roff,
                                                const int* __restrict__ cpad,
                                                float* __restrict__ out) {
  __shared__ __align__(16) unsigned short As[2][4096];
  __shared__ __align__(16) unsigned short Bs[2][4096];
  const int e = blockIdx.z, yb = blockIdx.y, bx = blockIdx.x, tid = threadIdx.x;
  if (yb * 128 >= cpad[e]) return;
  const int base = roff[e];
  const unsigned short* hA = h + (size_t)(2 * TOK + base) * HID;
  const unsigned short* w2s = w2b + (size_t)(NSH + e) * DIMN * HID;
  const int wv = tid >> 6, lane = tid & 63, wm = wv >> 1, wn = wv & 1;
  const int kc = (tid & 3) * 8;
  const unsigned short* ap0 = hA + ((size_t)yb * 128 + (tid >> 2)) * HID + kc;
  const unsigned short* ap1 = ap0 + (size_t)64 * HID;
  const unsigned short* bp0 = w2s + ((size_t)bx * 128 + (tid >> 2)) * HID + kc;
  const unsigned short* bp1 = bp0 + (size_t)64 * HID;
  f32x4 acc[4][4] = {};
#define STAGE2R(buf, kt) do {                                 \
    int _ko = (kt) * 32;                                      \
    gl_lds16(ap0 + _ko, &As[buf][wv * 512]);                  \
    gl_lds16(ap1 + _ko, &As[buf][2048 + wv * 512]);           \
    gl_lds16(bp0 + _ko, &Bs[buf][wv * 512]);                  \
    gl_lds16(bp1 + _ko, &Bs[buf][2048 + wv * 512]);           \
  } while (0)
  STAGE2R(0, 0);
  const int aoff = (wm * 64 + (lane & 15)) * 32 + (lane >> 4) * 8;
  const int boff = (wn * 64 + (lane & 15)) * 32 + (lane >> 4) * 8;
  int cur = 0;
  for (int kt = 0; kt < HID / 32; ++kt) {
    __syncthreads();
    if (kt + 1 < HID / 32) STAGE2R(cur ^ 1, kt + 1);
    const unsigned short* Ab = &As[cur][aoff];
    const unsigned short* Bb = &Bs[cur][boff];
    s16x8 af[4], bfv[4];
#pragma unroll
    for (int f = 0; f < 4; ++f) af[f] = *(const s16x8*)(Ab + f * 512);
#pragma unroll
    for (int f = 0; f < 4; ++f) bfv[f] = *(const s16x8*)(Bb + f * 512);
#pragma unroll
    for (int i = 0; i < 4; ++i)
#pragma unroll
      for (int j = 0; j < 4; ++j)
        acc[i][j] = __builtin_amdgcn_mfma_f32_16x16x32_bf16(af[i], bfv[j], acc[i][j], 0, 0, 0);
    cur ^= 1;
  }
#undef STAGE2R
  const int lr = lane & 15, lq = lane >> 4;
#pragma unroll
  for (int mf = 0; mf < 4; ++mf) {
    const int lrow = yb * 128 + wm * 64 + mf * 16 + lq * 4;
#pragma unroll
    for (int r = 0; r < 4; ++r) {
      const int g = base + lrow + r;
      const int t = glist[g];
      const float wgt = gw[g];
#pragma unroll
      for (int nf = 0; nf < 4; ++nf) {
        const int col = bx * 128 + wn * 64 + nf * 16 + lr;
        atomicAdd(&out[(size_t)t * DIMN + col], wgt * acc[mf][nf][r]);
      }
    }
  }
}

// ---------------- ws layout ----------------
static const size_t OFF_XB    = 0;
static const size_t OFF_W13   = OFF_XB + (size_t)TOK * DIMN * 2;
static const size_t OFF_W2    = OFF_W13 + (size_t)NSLOT * 2560 * DIMN * 2;
static const size_t OFF_H     = OFF_W2 + (size_t)NSLOT * DIMN * HID * 2;
static const size_t OFF_GLIST = OFF_H + (size_t)(2 * TOK + RCAP) * HID * 2;
static const size_t OFF_GW    = OFF_GLIST + (size_t)RCAPG * 4;
static const size_t OFF_TIDX  = OFF_GW + (size_t)RCAPG * 4;
static const size_t OFF_TW    = OFF_TIDX + (size_t)TOK * 2 * 4;
static const size_t OFF_CNT   = OFF_TW + (size_t)TOK * 2 * 4;
static const size_t OFF_CNT2  = OFF_CNT + 32;
static const size_t OFF_ROFF  = OFF_CNT2 + 32;
static const size_t OFF_CPAD  = OFF_ROFF + 32;
static const size_t OFF_ENT   = OFF_CPAD + 32;

extern "C" void kernel_launch(void* const* d_in, const int* in_sizes, int n_in,
                              void* d_out, int out_size, void* d_ws, size_t ws_size,
                              hipStream_t stream) {
  const float* x    = (const float*)d_in[0];
  const float* emb  = (const float*)d_in[1];
  const float* bias = (const float*)d_in[2];
  const float* w1   = (const float*)d_in[3];
  const float* w2   = (const float*)d_in[4];
  const float* w3   = (const float*)d_in[5];
  const float* sw1  = (const float*)d_in[6];
  const float* sw2  = (const float*)d_in[7];
  const float* sw3  = (const float*)d_in[8];
  float* out = (float*)d_out;
  char* ws = (char*)d_ws;
  unsigned short* xb   = (unsigned short*)(ws + OFF_XB);
  unsigned short* w13b = (unsigned short*)(ws + OFF_W13);
  unsigned short* w2b  = (unsigned short*)(ws + OFF_W2);
  unsigned short* h    = (unsigned short*)(ws + OFF_H);
  int*   glist = (int*)(ws + OFF_GLIST);
  float* gw    = (float*)(ws + OFF_GW);
  int*   tidx  = (int*)(ws + OFF_TIDX);
  float* tw    = (float*)(ws + OFF_TW);
  int*   cnt   = (int*)(ws + OFF_CNT);
  int*   cnt2  = (int*)(ws + OFF_CNT2);
  int*   roff  = (int*)(ws + OFF_ROFF);
  int*   cpad  = (int*)(ws + OFF_CPAD);
  double* ent  = (double*)(ws + OFF_ENT);

  hipFuncSetAttribute((const void*)k_gemm1_8ph, hipFuncAttributeMaxDynamicSharedMemorySize, 131072);

  k_zero<<<(RCAPG + 255) / 256, 256, 0, stream>>>(glist, gw, cnt, cnt2, ent);
  k_cvt_x<<<(TOK * DIMN / 4) / 256, 256, 0, stream>>>(x, xb);
  k_cvt_w13<<<dim3(2560, NSLOT), 256, 0, stream>>>(w1, w3, sw1, sw3, w13b);
  k_cvt_w2<<<dim3(DIMN, NSLOT), 256, 0, stream>>>(w2, sw2, w2b);
  k_gate<<<TOK / 4, 256, 0, stream>>>(x, emb, bias, tidx, tw, cnt, ent);
  k_offsets<<<1, 64, 0, stream>>>(cnt, roff, cpad, ent, out + (size_t)TOK * DIMN);
  k_scatter<<<TOK / 256, 256, 0, stream>>>(tidx, tw, roff, cnt2, glist, gw);
  k_gemm1_8ph<<<dim3(2560 / 256, TOK / 256, NSLOT), 512, 131072, stream>>>(xb, w13b, h, glist, roff, cpad);
  k_gemm2s<<<dim3(DIMN / 128, TOK / 128), 256, 0, stream>>>(h, w2b, out);
  k_gemm2r<<<dim3(DIMN / 128, TOK / 128, NEXP), 256, 0, stream>>>(h, w2b, glist, gw, roff, cpad, out);
}

// Round 5
// 749.334 us; speedup vs baseline: 1.1504x; 1.0916x over previous
//
#include <hip/hip_runtime.h>
#include <math.h>

#define TOK 8192
#define DIMN 1024
#define HID 1280
#define NEXP 8
#define NSH 2
#define NSLOT 10
#define RCAP 17408          // 16384 + 8*128 max padding
#define RCAPG (RCAP + 256)  // glist slack for 256-row gemm1 tiles
#define G1_NT (DIMN / 64)   // 16 K-tiles of 64

typedef short s16x8 __attribute__((ext_vector_type(8)));
typedef float f32x4 __attribute__((ext_vector_type(4)));

// f32 -> bf16 RNE
__device__ __forceinline__ unsigned short f2bf(float f) {
  unsigned u = __float_as_uint(f);
  u += 0x7fffu + ((u >> 16) & 1u);
  return (unsigned short)(u >> 16);
}
__device__ __forceinline__ float bf2f(unsigned short u) {
  return __uint_as_float((unsigned)u << 16);
}

__device__ __forceinline__ void gl_lds16(const void* g, void* l) {
  typedef __attribute__((address_space(1))) const unsigned int guint;
  typedef __attribute__((address_space(3))) unsigned int luint;
  __builtin_amdgcn_global_load_lds((guint*)g, (luint*)l, 16, 0, 0);
}

// ---------------- init / zero ----------------
__global__ __launch_bounds__(256) void k_zero(int* __restrict__ glist,
                                              int* __restrict__ cnt, int* __restrict__ cnt2,
                                              double* __restrict__ ent_acc) {
  int i = blockIdx.x * 256 + threadIdx.x;
  if (i < RCAPG) glist[i] = 0;
  if (i < NEXP) { cnt[i] = 0; cnt2[i] = 0; }
  if (i == 0) *ent_acc = 0.0;
}

// ---------------- converts ----------------
__global__ __launch_bounds__(256) void k_cvt_x(const float* __restrict__ x,
                                               unsigned short* __restrict__ xb) {
  int i = blockIdx.x * 256 + threadIdx.x;
  float4 v = ((const float4*)x)[i];
  ushort4 o;
  o.x = f2bf(v.x); o.y = f2bf(v.y); o.z = f2bf(v.z); o.w = f2bf(v.w);
  ((ushort4*)xb)[i] = o;
}

// w13b[slot][2560][1024]: row r: g=r>>5, which=(r>>4)&1, i=r&15 -> (which?w3:w1) row g*16+i
__global__ __launch_bounds__(256) void k_cvt_w13(const float* __restrict__ w1, const float* __restrict__ w3,
                                                 const float* __restrict__ sw1, const float* __restrict__ sw3,
                                                 unsigned short* __restrict__ w13b) {
  const int r = blockIdx.x;
  const int s = blockIdx.y;
  const int which = (r >> 4) & 1;
  const int srow = ((r >> 5) << 4) + (r & 15);
  const float* src;
  if (s < NSH) src = (which ? sw3 : sw1) + ((size_t)s * HID + srow) * DIMN;
  else         src = (which ? w3 : w1) + ((size_t)(s - NSH) * HID + srow) * DIMN;
  unsigned short* dst = w13b + ((size_t)s * 2560 + r) * DIMN;
  int c = threadIdx.x * 4;
  float4 v = *(const float4*)(src + c);
  ushort4 o;
  o.x = f2bf(v.x); o.y = f2bf(v.y); o.z = f2bf(v.z); o.w = f2bf(v.w);
  *(ushort4*)(dst + c) = o;
}

__global__ __launch_bounds__(256) void k_cvt_w2(const float* __restrict__ w2, const float* __restrict__ sw2,
                                                unsigned short* __restrict__ w2b) {
  const int d = blockIdx.x;
  const int s = blockIdx.y;
  const float* src = (s < NSH) ? sw2 + ((size_t)s * DIMN + d) * HID
                               : w2 + ((size_t)(s - NSH) * DIMN + d) * HID;
  unsigned short* dst = w2b + ((size_t)s * DIMN + d) * HID;
  for (int j = threadIdx.x; j < HID / 4; j += 256) {
    float4 v = ((const float4*)src)[j];
    ushort4 o;
    o.x = f2bf(v.x); o.y = f2bf(v.y); o.z = f2bf(v.z); o.w = f2bf(v.w);
    ((ushort4*)dst)[j] = o;
  }
}

// ---------------- gate (f32 semantics: sigmoid saturation + lowest-index tie-break) ----------------
__global__ __launch_bounds__(256) void k_gate(const float* __restrict__ x, const float* __restrict__ emb,
                                              const float* __restrict__ bias, int* __restrict__ tidx,
                                              float* __restrict__ tw, int* __restrict__ cnt,
                                              double* __restrict__ ent_acc) {
  const int lane = threadIdx.x & 63;
  const int wv = threadIdx.x >> 6;
  const int t = blockIdx.x * 4 + wv;
  const float* xr = x + (size_t)t * DIMN;
  float acc[NEXP];
#pragma unroll
  for (int e = 0; e < NEXP; ++e) acc[e] = 0.0f;
  for (int i = 0; i < DIMN / 64; ++i) {
    float xv = xr[lane + 64 * i];
#pragma unroll
    for (int e = 0; e < NEXP; ++e)
      acc[e] = fmaf(xv, emb[e * DIMN + lane + 64 * i], acc[e]);
  }
#pragma unroll
  for (int e = 0; e < NEXP; ++e) {
#pragma unroll
    for (int off = 32; off > 0; off >>= 1) acc[e] += __shfl_xor(acc[e], off);
  }
  __shared__ double ebuf[4];
  if (lane == 0) {
    float s[NEXP];
#pragma unroll
    for (int e = 0; e < NEXP; ++e) s[e] = 1.0f / (1.0f + expf(-acc[e])) + bias[e];
    int i0 = 0;
    for (int e = 1; e < NEXP; ++e) if (s[e] > s[i0]) i0 = e;
    int i1 = -1;
    for (int e = 0; e < NEXP; ++e) {
      if (e == i0) continue;
      if (i1 < 0 || s[e] > s[i1]) i1 = e;
    }
    float v0 = s[i0], v1 = s[i1];
    float inv = 1.0f / (v0 + v1);
    float w0 = v0 * inv, w1 = v1 * inv;
    tidx[2 * t] = i0; tidx[2 * t + 1] = i1;
    tw[2 * t] = w0; tw[2 * t + 1] = w1;
    atomicAdd(&cnt[i0], 1);
    atomicAdd(&cnt[i1], 1);
    ebuf[wv] = -(double)(w0 * logf(w0) + w1 * logf(w1));
  }
  __syncthreads();
  if (threadIdx.x == 0) atomicAdd(ent_acc, ebuf[0] + ebuf[1] + ebuf[2] + ebuf[3]);
}

// ---------------- offsets + tail finalize ----------------
__global__ void k_offsets(const int* __restrict__ cnt, int* __restrict__ roff, int* __restrict__ cpad,
                          const double* __restrict__ ent_acc, float* __restrict__ out_tail) {
  if (threadIdx.x == 0 && blockIdx.x == 0) {
    int off = 0;
    for (int e = 0; e < NEXP; ++e) {
      roff[e] = off;
      int cp = (cnt[e] + 127) & ~127;
      cpad[e] = cp;
      off += cp;
    }
    out_tail[0] = 0.0f;
    out_tail[1] = (float)(*ent_acc * (1.0 / TOK));
  }
}

// ---------------- scatter: compact lists + per-token positions ----------------
__global__ __launch_bounds__(256) void k_scatter(const int* __restrict__ tidx,
                                                 const int* __restrict__ roff, int* __restrict__ cnt2,
                                                 int* __restrict__ glist, int* __restrict__ pos) {
  int t = blockIdx.x * 256 + threadIdx.x;
#pragma unroll
  for (int j = 0; j < 2; ++j) {
    int e = tidx[2 * t + j];
    int p = atomicAdd(&cnt2[e], 1);
    int g = roff[e] + p;
    glist[g] = t;
    pos[2 * t + j] = g;
  }
}

// ---------------- GEMM1, 8-phase 256x256x64 ----------------
// Round-5 changes: (1) NO sched_barrier fences (ds_reads are compiler-visible; rule #18
// applies to inline-asm reads only) — template-faithful phase:
// {reads, stage, [vmcnt], BARR, lgkmcnt(0), setprio, MFMA, setprio, BARR}.
// (2) vmcnt re-derived: VMW(6) after ph0 stage (retires A1/B1 of cur tile);
// VMW(8) at ph3 (retires A0/B0 of next tile). Invariant: 8 outstanding at iter entry.
__global__ __launch_bounds__(512, 2) void k_gemm1_8ph(const unsigned short* __restrict__ xb,
                                                      const unsigned short* __restrict__ w13b,
                                                      unsigned short* __restrict__ h,
                                                      const int* __restrict__ glist,
                                                      const int* __restrict__ roff,
                                                      const int* __restrict__ cpad) {
  extern __shared__ __align__(16) char smem[];
  const int slot = blockIdx.z, yb = blockIdx.y, bx = blockIdx.x;
  const int tid = threadIdx.x;
  const int w = tid >> 6, lane = tid & 63;
  int hrow0, rowlim;
  int tokq[4];
  const int trbase = w * 8 + (lane >> 3);
  if (slot < NSH) {
    hrow0 = slot * TOK + yb * 256;
    rowlim = 256;
#pragma unroll
    for (int q = 0; q < 4; ++q) tokq[q] = yb * 256 + q * 64 + trbase;
  } else {
    const int e = slot - NSH;
    const int cp = cpad[e];
    if (yb * 256 >= cp) return;
    const int base = roff[e];
    hrow0 = 2 * TOK + base + yb * 256;
    rowlim = cp - yb * 256; if (rowlim > 256) rowlim = 256;
#pragma unroll
    for (int q = 0; q < 4; ++q) tokq[q] = glist[base + yb * 256 + q * 64 + trbase];
  }
  // stage source: per-lane in-row byte offset, pre-swizzled (dest byte bits 8-10 = lane4, lane5, w&1)
  const int srcoff = ((lane & 7) * 16) ^ (((lane >> 4) & 1) << 4) ^ (((lane >> 5) & 1) << 5) ^ ((w & 1) << 6);
  const char* aptr[4];
#pragma unroll
  for (int q = 0; q < 4; ++q) aptr[q] = (const char*)xb + (size_t)tokq[q] * 2048 + srcoff;
  const char* w13s = (const char*)w13b + (size_t)slot * 2560 * 2048;
  const int crow0 = (w >> 2) * 64 + (w & 3) * 8 + (lane >> 3);
  const char* bptr[2];
#pragma unroll
  for (int nq = 0; nq < 2; ++nq)
    bptr[nq] = w13s + (size_t)(bx * 256 + crow0 + nq * 32) * 2048 + srcoff;
  // wave-uniform LDS stage dest bases (within a buf)
  const int dA = (w * 8) * 128;
  const int dB = 32768 + (((w >> 2) * 64 + (w & 3) * 8) * 128);

#define STA(BB, MH, TT) do {                               \
    char* _d = smem + (BB) + dA + (MH) * 8192;             \
    gl_lds16(aptr[MH] + (TT) * 128, _d);                   \
    gl_lds16(aptr[(MH) + 2] + (TT) * 128, _d + 16384);     \
  } while (0)
#define STB(BB, NQ, TT) do {                               \
    char* _d = smem + (BB) + dB + (NQ) * 4096;             \
    gl_lds16(bptr[NQ] + (TT) * 128, _d);                   \
    gl_lds16(bptr[NQ] + 262144 + (TT) * 128, _d + 16384);  \
  } while (0)

  // fragment read bases; kswz = swizzle folded to lane-constant XOR (row bits 1-3 = lane bits 1-3)
  const int lr = lane & 15, lq = lane >> 4;
  const int kswz = (((lr >> 1) & 1) << 4) | (((lr >> 2) & 1) << 5) | (((lr >> 3) & 1) << 6);
  const int wm = w >> 2, wn = w & 3;  // 2(M) x 4(N) wave grid; per-wave out 128x64
  const int aoffb = (wm * 128 + lr) * 128 + lq * 16;
  const int boffb = 32768 + (wn * 64 + lr) * 128 + lq * 16;

#define RD_A(BB, MH) do {                                                                            \
    _Pragma("unroll")                                                                                \
    for (int mf = 0; mf < 4; ++mf)                                                                   \
      _Pragma("unroll")                                                                              \
      for (int ks = 0; ks < 2; ++ks)                                                                 \
        areg[mf][ks] = *(const s16x8*)(smem + (((BB) + aoffb + (MH) * 8192 + mf * 2048 + ks * 64) ^ kswz)); \
  } while (0)
#define RD_B(BB, NQ, RG) do {                                                                        \
    _Pragma("unroll")                                                                                \
    for (int nf = 0; nf < 2; ++nf)                                                                   \
      _Pragma("unroll")                                                                              \
      for (int ks = 0; ks < 2; ++ks)                                                                 \
        RG[nf][ks] = *(const s16x8*)(smem + (((BB) + boffb + (NQ) * 4096 + nf * 2048 + ks * 64) ^ kswz)); \
  } while (0)
#define MFMA16(MH, RG, NQ) do {                                                                      \
    __builtin_amdgcn_s_setprio(1);                                                                   \
    _Pragma("unroll")                                                                                \
    for (int mf = 0; mf < 4; ++mf)                                                                   \
      _Pragma("unroll")                                                                              \
      for (int nf = 0; nf < 2; ++nf)                                                                 \
        _Pragma("unroll")                                                                            \
        for (int ks = 0; ks < 2; ++ks)                                                               \
          acc[(MH) * 4 + mf][(NQ) * 2 + nf] = __builtin_amdgcn_mfma_f32_16x16x32_bf16(               \
              areg[mf][ks], RG[nf][ks], acc[(MH) * 4 + mf][(NQ) * 2 + nf], 0, 0, 0);                 \
    __builtin_amdgcn_s_setprio(0);                                                                   \
  } while (0)
#define VMW(N) asm volatile("s_waitcnt vmcnt(" #N ")" ::: "memory")
#define BARR() __builtin_amdgcn_s_barrier()
#define LGKM0() asm volatile("s_waitcnt lgkmcnt(0)" ::: "memory")

  // prologue: tile0 full + tile1 (A0, B0) = 12 loads; VMW(8) retires tile0 A0/B0
  STA(0, 0, 0); STB(0, 0, 0); STA(0, 1, 0); STB(0, 1, 0);
  STA(65536, 0, 1); STB(65536, 0, 1);
  VMW(8);
  BARR();

  f32x4 acc[8][4] = {};
  for (int j = 0; j < G1_NT; ++j) {
    const int bufb = (j & 1) << 16;
    const int bufo = bufb ^ 65536;
    const int t1 = (j + 1 < G1_NT) ? j + 1 : G1_NT - 1;  // clamped re-stage keeps vmcnt counts uniform
    const int t2 = (j + 2 < G1_NT) ? j + 2 : G1_NT - 1;
    s16x8 areg[4][2];
    s16x8 breg0[2][2], breg1[2][2];
    // ph0 (mh0,nq0)
    RD_A(bufb, 0);
    RD_B(bufb, 0, breg0);
    STA(bufo, 1, t1);
    VMW(6);              // retires A1(j), B1(j) before ph1/ph2 reads (post-barrier)
    BARR(); LGKM0();
    MFMA16(0, breg0, 0);
    BARR();
    // ph1 (mh0,nq1)
    RD_B(bufb, 1, breg1);
    STB(bufo, 1, t1);
    BARR(); LGKM0();
    MFMA16(0, breg1, 1);
    BARR();
    // ph2 (mh1,nq1): A half swapped; breg1 reused from ph1
    RD_A(bufb, 1);
    STA(bufb, 0, t2);
    BARR(); LGKM0();
    MFMA16(1, breg1, 1);
    BARR();
    // ph3 (mh1,nq0): zero ds_reads (breg0 cached since ph0)
    STB(bufb, 0, t2);
    VMW(8);              // retires A0(j+1), B0(j+1) for next ph0 reads
    BARR();
    MFMA16(1, breg0, 0);
    BARR();
  }
#undef STA
#undef STB
#undef RD_A
#undef RD_B
#undef MFMA16

  asm volatile("s_waitcnt vmcnt(0)" ::: "memory");
  // epilogue: silu(w1col)*w3col -> h (bf16); C frag: col=lane&15, row=lq*4+reg
#pragma unroll
  for (int m = 0; m < 8; ++m) {
    const int lrow0 = wm * 128 + (m >> 2) * 64 + (m & 3) * 16 + lq * 4;
#pragma unroll
    for (int p = 0; p < 2; ++p) {
      f32x4 a1 = acc[m][2 * p];
      f32x4 a3 = acc[m][2 * p + 1];
      const int hc = (bx * 8 + wn * 2 + p) * 16 + lr;
#pragma unroll
      for (int r = 0; r < 4; ++r) {
        const int lrow = lrow0 + r;
        if (lrow < rowlim) {
          float u = a1[r];
          float hv = (u / (1.f + __expf(-u))) * a3[r];
          h[(size_t)(hrow0 + lrow) * HID + hc] = f2bf(hv);
        }
      }
    }
  }
#undef VMW
#undef BARR
#undef LGKM0
}

// ---------------- GEMM2 shared: out = 0.5*(h0@W2_0^T + h1@W2_1^T), K=2560 concat ----------------
__global__ __launch_bounds__(256) void k_gemm2s(const unsigned short* __restrict__ h,
                                                const unsigned short* __restrict__ w2b,
                                                float* __restrict__ out) {
  __shared__ __align__(16) unsigned short As[2][4096];
  __shared__ __align__(16) unsigned short Bs[2][4096];
  const int yb = blockIdx.y, bx = blockIdx.x, tid = threadIdx.x;
  const int wv = tid >> 6, lane = tid & 63, wm = wv >> 1, wn = wv & 1;
  const int kc = (tid & 3) * 8;
  const int tr = yb * 128 + (tid >> 2);
  const int nr = bx * 128 + (tid >> 2);
  const unsigned short* a0s0 = h + (size_t)tr * HID + kc;
  const unsigned short* a1s0 = h + (size_t)(tr + 64) * HID + kc;
  const unsigned short* a0s1 = h + (size_t)(TOK + tr) * HID + kc;
  const unsigned short* a1s1 = h + (size_t)(TOK + tr + 64) * HID + kc;
  const unsigned short* b0s0 = w2b + (size_t)nr * HID + kc;
  const unsigned short* b1s0 = b0s0 + (size_t)64 * HID;
  const unsigned short* b0s1 = w2b + (size_t)(DIMN + nr) * HID + kc;
  const unsigned short* b1s1 = b0s1 + (size_t)64 * HID;
  f32x4 acc[4][4] = {};
#define STAGE2S(buf, kt) do {                                             \
    int _k0 = (kt) * 32;                                                  \
    int _k = (_k0 < HID) ? _k0 : _k0 - HID;                               \
    const unsigned short* _a0 = (_k0 < HID) ? a0s0 : a0s1;                \
    const unsigned short* _a1 = (_k0 < HID) ? a1s0 : a1s1;                \
    const unsigned short* _b0 = (_k0 < HID) ? b0s0 : b0s1;                \
    const unsigned short* _b1 = (_k0 < HID) ? b1s0 : b1s1;                \
    gl_lds16(_a0 + _k, &As[buf][wv * 512]);                               \
    gl_lds16(_a1 + _k, &As[buf][2048 + wv * 512]);                        \
    gl_lds16(_b0 + _k, &Bs[buf][wv * 512]);                               \
    gl_lds16(_b1 + _k, &Bs[buf][2048 + wv * 512]);                        \
  } while (0)
  STAGE2S(0, 0);
  const int aoff = (wm * 64 + (lane & 15)) * 32 + (lane >> 4) * 8;
  const int boff = (wn * 64 + (lane & 15)) * 32 + (lane >> 4) * 8;
  int cur = 0;
  for (int kt = 0; kt < 2 * HID / 32; ++kt) {
    __syncthreads();
    if (kt + 1 < 2 * HID / 32) STAGE2S(cur ^ 1, kt + 1);
    const unsigned short* Ab = &As[cur][aoff];
    const unsigned short* Bb = &Bs[cur][boff];
    s16x8 af[4], bfv[4];
#pragma unroll
    for (int f = 0; f < 4; ++f) af[f] = *(const s16x8*)(Ab + f * 512);
#pragma unroll
    for (int f = 0; f < 4; ++f) bfv[f] = *(const s16x8*)(Bb + f * 512);
#pragma unroll
    for (int i = 0; i < 4; ++i)
#pragma unroll
      for (int j = 0; j < 4; ++j)
        acc[i][j] = __builtin_amdgcn_mfma_f32_16x16x32_bf16(af[i], bfv[j], acc[i][j], 0, 0, 0);
    cur ^= 1;
  }
#undef STAGE2S
  const int lr = lane & 15, lq = lane >> 4;
#pragma unroll
  for (int mf = 0; mf < 4; ++mf) {
    const int t = yb * 128 + wm * 64 + mf * 16 + lq * 4;
#pragma unroll
    for (int nf = 0; nf < 4; ++nf) {
      const int col = bx * 128 + wn * 64 + nf * 16 + lr;
#pragma unroll
      for (int r = 0; r < 4; ++r)
        out[(size_t)(t + r) * DIMN + col] = 0.5f * acc[mf][nf][r];
    }
  }
}

// ---------------- GEMM2 routed (atomic-free): ro[g] = h_e[g] @ W2_e^T (bf16) ----------------
__global__ __launch_bounds__(256) void k_gemm2r(const unsigned short* __restrict__ h,
                                                const unsigned short* __restrict__ w2b,
                                                const int* __restrict__ roff,
                                                const int* __restrict__ cpad,
                                                unsigned short* __restrict__ ro) {
  __shared__ __align__(16) unsigned short As[2][4096];
  __shared__ __align__(16) unsigned short Bs[2][4096];
  const int e = blockIdx.z, yb = blockIdx.y, bx = blockIdx.x, tid = threadIdx.x;
  if (yb * 128 >= cpad[e]) return;
  const int base = roff[e];
  const unsigned short* hA = h + (size_t)(2 * TOK + base) * HID;
  const unsigned short* w2s = w2b + (size_t)(NSH + e) * DIMN * HID;
  const int wv = tid >> 6, lane = tid & 63, wm = wv >> 1, wn = wv & 1;
  const int kc = (tid & 3) * 8;
  const unsigned short* ap0 = hA + ((size_t)yb * 128 + (tid >> 2)) * HID + kc;
  const unsigned short* ap1 = ap0 + (size_t)64 * HID;
  const unsigned short* bp0 = w2s + ((size_t)bx * 128 + (tid >> 2)) * HID + kc;
  const unsigned short* bp1 = bp0 + (size_t)64 * HID;
  f32x4 acc[4][4] = {};
#define STAGE2R(buf, kt) do {                                 \
    int _ko = (kt) * 32;                                      \
    gl_lds16(ap0 + _ko, &As[buf][wv * 512]);                  \
    gl_lds16(ap1 + _ko, &As[buf][2048 + wv * 512]);           \
    gl_lds16(bp0 + _ko, &Bs[buf][wv * 512]);                  \
    gl_lds16(bp1 + _ko, &Bs[buf][2048 + wv * 512]);           \
  } while (0)
  STAGE2R(0, 0);
  const int aoff = (wm * 64 + (lane & 15)) * 32 + (lane >> 4) * 8;
  const int boff = (wn * 64 + (lane & 15)) * 32 + (lane >> 4) * 8;
  int cur = 0;
  for (int kt = 0; kt < HID / 32; ++kt) {
    __syncthreads();
    if (kt + 1 < HID / 32) STAGE2R(cur ^ 1, kt + 1);
    const unsigned short* Ab = &As[cur][aoff];
    const unsigned short* Bb = &Bs[cur][boff];
    s16x8 af[4], bfv[4];
#pragma unroll
    for (int f = 0; f < 4; ++f) af[f] = *(const s16x8*)(Ab + f * 512);
#pragma unroll
    for (int f = 0; f < 4; ++f) bfv[f] = *(const s16x8*)(Bb + f * 512);
#pragma unroll
    for (int i = 0; i < 4; ++i)
#pragma unroll
      for (int j = 0; j < 4; ++j)
        acc[i][j] = __builtin_amdgcn_mfma_f32_16x16x32_bf16(af[i], bfv[j], acc[i][j], 0, 0, 0);
    cur ^= 1;
  }
#undef STAGE2R
  const int lr = lane & 15, lq = lane >> 4;
#pragma unroll
  for (int mf = 0; mf < 4; ++mf) {
    const int lrow = yb * 128 + wm * 64 + mf * 16 + lq * 4;
#pragma unroll
    for (int r = 0; r < 4; ++r) {
      const int g = base + lrow + r;
#pragma unroll
      for (int nf = 0; nf < 4; ++nf) {
        const int col = bx * 128 + wn * 64 + nf * 16 + lr;
        ro[(size_t)g * DIMN + col] = f2bf(acc[mf][nf][r]);
      }
    }
  }
}

// ---------------- combine: out[t] += w0*ro[g0] + w1*ro[g1] ----------------
__global__ __launch_bounds__(256) void k_combine(const unsigned short* __restrict__ ro,
                                                 const int* __restrict__ pos,
                                                 const float* __restrict__ tw,
                                                 float* __restrict__ out) {
  const int t = blockIdx.x;
  const int g0 = pos[2 * t], g1 = pos[2 * t + 1];
  const float w0 = tw[2 * t], w1 = tw[2 * t + 1];
  const int c = threadIdx.x * 4;
  ushort4 r0 = *(const ushort4*)(ro + (size_t)g0 * DIMN + c);
  ushort4 r1 = *(const ushort4*)(ro + (size_t)g1 * DIMN + c);
  float4 o = *(float4*)(out + (size_t)t * DIMN + c);
  o.x += w0 * bf2f(r0.x) + w1 * bf2f(r1.x);
  o.y += w0 * bf2f(r0.y) + w1 * bf2f(r1.y);
  o.z += w0 * bf2f(r0.z) + w1 * bf2f(r1.z);
  o.w += w0 * bf2f(r0.w) + w1 * bf2f(r1.w);
  *(float4*)(out + (size_t)t * DIMN + c) = o;
}

// ---------------- ws layout ----------------
static const size_t OFF_XB    = 0;
static const size_t OFF_W13   = OFF_XB + (size_t)TOK * DIMN * 2;
static const size_t OFF_W2    = OFF_W13 + (size_t)NSLOT * 2560 * DIMN * 2;
static const size_t OFF_H     = OFF_W2 + (size_t)NSLOT * DIMN * HID * 2;
// ro (RCAPG x DIMN bf16 = 36.2 MB) aliases the shared-h region (2*TOK*HID*2 = 41.9 MB):
// gemm2s (sole reader of shared-h) completes before gemm2r writes ro. Stream order enforces.
static const size_t OFF_RO    = OFF_H;
static const size_t OFF_GLIST = OFF_H + (size_t)(2 * TOK + RCAP) * HID * 2;
static const size_t OFF_POS   = OFF_GLIST + (size_t)RCAPG * 4;
static const size_t OFF_TIDX  = OFF_POS + (size_t)TOK * 2 * 4;
static const size_t OFF_TW    = OFF_TIDX + (size_t)TOK * 2 * 4;
static const size_t OFF_CNT   = OFF_TW + (size_t)TOK * 2 * 4;
static const size_t OFF_CNT2  = OFF_CNT + 32;
static const size_t OFF_ROFF  = OFF_CNT2 + 32;
static const size_t OFF_CPAD  = OFF_ROFF + 32;
static const size_t OFF_ENT   = OFF_CPAD + 32;

extern "C" void kernel_launch(void* const* d_in, const int* in_sizes, int n_in,
                              void* d_out, int out_size, void* d_ws, size_t ws_size,
                              hipStream_t stream) {
  const float* x    = (const float*)d_in[0];
  const float* emb  = (const float*)d_in[1];
  const float* bias = (const float*)d_in[2];
  const float* w1   = (const float*)d_in[3];
  const float* w2   = (const float*)d_in[4];
  const float* w3   = (const float*)d_in[5];
  const float* sw1  = (const float*)d_in[6];
  const float* sw2  = (const float*)d_in[7];
  const float* sw3  = (const float*)d_in[8];
  float* out = (float*)d_out;
  char* ws = (char*)d_ws;
  unsigned short* xb   = (unsigned short*)(ws + OFF_XB);
  unsigned short* w13b = (unsigned short*)(ws + OFF_W13);
  unsigned short* w2b  = (unsigned short*)(ws + OFF_W2);
  unsigned short* h    = (unsigned short*)(ws + OFF_H);
  unsigned short* ro   = (unsigned short*)(ws + OFF_RO);
  int*   glist = (int*)(ws + OFF_GLIST);
  int*   pos   = (int*)(ws + OFF_POS);
  int*   tidx  = (int*)(ws + OFF_TIDX);
  float* tw    = (float*)(ws + OFF_TW);
  int*   cnt   = (int*)(ws + OFF_CNT);
  int*   cnt2  = (int*)(ws + OFF_CNT2);
  int*   roff  = (int*)(ws + OFF_ROFF);
  int*   cpad  = (int*)(ws + OFF_CPAD);
  double* ent  = (double*)(ws + OFF_ENT);

  hipFuncSetAttribute((const void*)k_gemm1_8ph, hipFuncAttributeMaxDynamicSharedMemorySize, 131072);

  k_zero<<<(RCAPG + 255) / 256, 256, 0, stream>>>(glist, cnt, cnt2, ent);
  k_cvt_x<<<(TOK * DIMN / 4) / 256, 256, 0, stream>>>(x, xb);
  k_cvt_w13<<<dim3(2560, NSLOT), 256, 0, stream>>>(w1, w3, sw1, sw3, w13b);
  k_cvt_w2<<<dim3(DIMN, NSLOT), 256, 0, stream>>>(w2, sw2, w2b);
  k_gate<<<TOK / 4, 256, 0, stream>>>(x, emb, bias, tidx, tw, cnt, ent);
  k_offsets<<<1, 64, 0, stream>>>(cnt, roff, cpad, ent, out + (size_t)TOK * DIMN);
  k_scatter<<<TOK / 256, 256, 0, stream>>>(tidx, roff, cnt2, glist, pos);
  k_gemm1_8ph<<<dim3(2560 / 256, TOK / 256, NSLOT), 512, 131072, stream>>>(xb, w13b, h, glist, roff, cpad);
  k_gemm2s<<<dim3(DIMN / 128, TOK / 128), 256, 0, stream>>>(h, w2b, out);
  k_gemm2r<<<dim3(DIMN / 128, TOK / 128, NEXP), 256, 0, stream>>>(h, w2b, roff, cpad, ro);
  k_combine<<<TOK, 256, 0, stream>>>(ro, pos, tw, out);
}

// Round 6
// 690.093 us; speedup vs baseline: 1.2491x; 1.0858x over previous
//
#include <hip/hip_runtime.h>
#include <math.h>

#define TOK 8192
#define DIMN 1024
#define HID 1280
#define NEXP 8
#define NSH 2
#define NSLOT 10
#define RCAP 17408          // 16384 + 8*128 max padding
#define RCAPG (RCAP + 256)  // glist slack for 256-row tiles
#define G1_NT (DIMN / 64)   // 16 K-tiles of 64 for gemm1
#define NGATE (TOK / 4)     // gate blocks

typedef short s16x8 __attribute__((ext_vector_type(8)));
typedef float f32x4 __attribute__((ext_vector_type(4)));

// f32 -> bf16 RNE
__device__ __forceinline__ unsigned short f2bf(float f) {
  unsigned u = __float_as_uint(f);
  u += 0x7fffu + ((u >> 16) & 1u);
  return (unsigned short)(u >> 16);
}
__device__ __forceinline__ float bf2f(unsigned short u) {
  return __uint_as_float((unsigned)u << 16);
}

__device__ __forceinline__ void gl_lds16(const void* g, void* l) {
  typedef __attribute__((address_space(1))) const unsigned int guint;
  typedef __attribute__((address_space(3))) unsigned int luint;
  __builtin_amdgcn_global_load_lds((guint*)g, (luint*)l, 16, 0, 0);
}

// ---------------- init / zero ----------------
__global__ __launch_bounds__(256) void k_zero(int* __restrict__ glist,
                                              int* __restrict__ cnt, int* __restrict__ cnt2) {
  int i = blockIdx.x * 256 + threadIdx.x;
  if (i < RCAPG) glist[i] = 0;
  if (i < NEXP) { cnt[i] = 0; cnt2[i] = 0; }
}

// ---------------- converts ----------------
__global__ __launch_bounds__(256) void k_cvt_x(const float* __restrict__ x,
                                               unsigned short* __restrict__ xb) {
  int i = blockIdx.x * 256 + threadIdx.x;
  float4 v = ((const float4*)x)[i];
  ushort4 o;
  o.x = f2bf(v.x); o.y = f2bf(v.y); o.z = f2bf(v.z); o.w = f2bf(v.w);
  ((ushort4*)xb)[i] = o;
}

// merged weight convert: r<2560 -> w13b row (interleaved w1/w3 16-col groups); else w2b row
__global__ __launch_bounds__(256) void k_cvt_w(const float* __restrict__ w1, const float* __restrict__ w3,
                                               const float* __restrict__ sw1, const float* __restrict__ sw3,
                                               const float* __restrict__ w2, const float* __restrict__ sw2,
                                               unsigned short* __restrict__ w13b,
                                               unsigned short* __restrict__ w2b) {
  const int r = blockIdx.x;
  const int s = blockIdx.y;
  if (r < 2560) {
    const int which = (r >> 4) & 1;
    const int srow = ((r >> 5) << 4) + (r & 15);
    const float* src;
    if (s < NSH) src = (which ? sw3 : sw1) + ((size_t)s * HID + srow) * DIMN;
    else         src = (which ? w3 : w1) + ((size_t)(s - NSH) * HID + srow) * DIMN;
    unsigned short* dst = w13b + ((size_t)s * 2560 + r) * DIMN;
    int c = threadIdx.x * 4;
    float4 v = *(const float4*)(src + c);
    ushort4 o;
    o.x = f2bf(v.x); o.y = f2bf(v.y); o.z = f2bf(v.z); o.w = f2bf(v.w);
    *(ushort4*)(dst + c) = o;
  } else {
    const int d = r - 2560;
    const float* src = (s < NSH) ? sw2 + ((size_t)s * DIMN + d) * HID
                                 : w2 + ((size_t)(s - NSH) * DIMN + d) * HID;
    unsigned short* dst = w2b + ((size_t)s * DIMN + d) * HID;
    for (int c = threadIdx.x * 4; c < HID; c += 1024) {
      float4 v = *(const float4*)(src + c);
      ushort4 o;
      o.x = f2bf(v.x); o.y = f2bf(v.y); o.z = f2bf(v.z); o.w = f2bf(v.w);
      *(ushort4*)(dst + c) = o;
    }
  }
}

// ---------------- gate (f32 semantics preserved EXACTLY; no global atomics) ----------------
__global__ __launch_bounds__(256) void k_gate(const float* __restrict__ x, const float* __restrict__ emb,
                                              const float* __restrict__ bias, int* __restrict__ tidx,
                                              float* __restrict__ tw, float* __restrict__ entp) {
  const int lane = threadIdx.x & 63;
  const int wv = threadIdx.x >> 6;
  const int t = blockIdx.x * 4 + wv;
  const float* xr = x + (size_t)t * DIMN;
  float acc[NEXP];
#pragma unroll
  for (int e = 0; e < NEXP; ++e) acc[e] = 0.0f;
  for (int i = 0; i < DIMN / 64; ++i) {
    float xv = xr[lane + 64 * i];
#pragma unroll
    for (int e = 0; e < NEXP; ++e)
      acc[e] = fmaf(xv, emb[e * DIMN + lane + 64 * i], acc[e]);
  }
#pragma unroll
  for (int e = 0; e < NEXP; ++e) {
#pragma unroll
    for (int off = 32; off > 0; off >>= 1) acc[e] += __shfl_xor(acc[e], off);
  }
  __shared__ float ebuf[4];
  if (lane == 0) {
    float s[NEXP];
#pragma unroll
    for (int e = 0; e < NEXP; ++e) s[e] = 1.0f / (1.0f + expf(-acc[e])) + bias[e];
    int i0 = 0;
    for (int e = 1; e < NEXP; ++e) if (s[e] > s[i0]) i0 = e;   // strict >: lowest index wins ties
    int i1 = -1;
    for (int e = 0; e < NEXP; ++e) {
      if (e == i0) continue;
      if (i1 < 0 || s[e] > s[i1]) i1 = e;
    }
    float v0 = s[i0], v1 = s[i1];
    float inv = 1.0f / (v0 + v1);
    float w0 = v0 * inv, w1 = v1 * inv;
    tidx[2 * t] = i0; tidx[2 * t + 1] = i1;
    tw[2 * t] = w0; tw[2 * t + 1] = w1;
    ebuf[wv] = -(w0 * logf(w0) + w1 * logf(w1));
  }
  __syncthreads();
  if (threadIdx.x == 0) entp[blockIdx.x] = ebuf[0] + ebuf[1] + ebuf[2] + ebuf[3];
}

// ---------------- count: LDS histogram, 8 global atomics per block ----------------
__global__ __launch_bounds__(256) void k_count(const int* __restrict__ tidx, int* __restrict__ cnt) {
  __shared__ int hist[NEXP];
  const int tid = threadIdx.x;
  if (tid < NEXP) hist[tid] = 0;
  __syncthreads();
  const int t = blockIdx.x * 256 + tid;
  atomicAdd(&hist[tidx[2 * t]], 1);
  atomicAdd(&hist[tidx[2 * t + 1]], 1);
  __syncthreads();
  if (tid < NEXP) atomicAdd(&cnt[tid], hist[tid]);
}

// ---------------- offsets + entropy reduce + tail finalize ----------------
__global__ __launch_bounds__(256) void k_offsets(const int* __restrict__ cnt, int* __restrict__ roff,
                                                 int* __restrict__ cpad, const float* __restrict__ entp,
                                                 float* __restrict__ out_tail) {
  __shared__ float red[256];
  float s = 0.f;
  for (int i = threadIdx.x; i < NGATE; i += 256) s += entp[i];
  red[threadIdx.x] = s;
  __syncthreads();
  for (int st = 128; st > 0; st >>= 1) {
    if (threadIdx.x < st) red[threadIdx.x] += red[threadIdx.x + st];
    __syncthreads();
  }
  if (threadIdx.x == 0) {
    int off = 0;
    for (int e = 0; e < NEXP; ++e) {
      roff[e] = off;
      int cp = (cnt[e] + 127) & ~127;
      cpad[e] = cp;
      off += cp;
    }
    out_tail[0] = 0.f;
    out_tail[1] = red[0] / (float)TOK;
  }
}

// ---------------- scatter: LDS histogram + one range-claim atomic per (block,expert) ----------------
__global__ __launch_bounds__(256) void k_scatter(const int* __restrict__ tidx,
                                                 const int* __restrict__ roff, int* __restrict__ cnt2,
                                                 int* __restrict__ glist, int* __restrict__ pos) {
  __shared__ int hist[NEXP], base[NEXP], cur[NEXP];
  const int tid = threadIdx.x;
  if (tid < NEXP) { hist[tid] = 0; cur[tid] = 0; }
  __syncthreads();
  const int t = blockIdx.x * 256 + tid;
  const int e0 = tidx[2 * t], e1 = tidx[2 * t + 1];
  atomicAdd(&hist[e0], 1);
  atomicAdd(&hist[e1], 1);
  __syncthreads();
  if (tid < NEXP) base[tid] = atomicAdd(&cnt2[tid], hist[tid]);
  __syncthreads();
  int p0 = atomicAdd(&cur[e0], 1);
  int g0 = roff[e0] + base[e0] + p0;
  glist[g0] = t; pos[2 * t] = g0;
  int p1 = atomicAdd(&cur[e1], 1);
  int g1 = roff[e1] + base[e1] + p1;
  glist[g1] = t; pos[2 * t + 1] = g1;
}

// ---------------- GEMM1, 4-phase 256x256x64 + T1 XCD chunk swizzle ----------------
__global__ __launch_bounds__(512, 2) void k_gemm1_8ph(const unsigned short* __restrict__ xb,
                                                      const unsigned short* __restrict__ w13b,
                                                      unsigned short* __restrict__ h,
                                                      const int* __restrict__ glist,
                                                      const int* __restrict__ roff,
                                                      const int* __restrict__ cpad) {
  extern __shared__ __align__(16) char smem[];
  // T1: bijective chunked swizzle; grid (10,64,10)=6400, 6400%8==0, chunk=800
  const int lin = blockIdx.x + blockIdx.y * 10 + blockIdx.z * 640;
  const int swz = (lin & 7) * 800 + (lin >> 3);
  const int bx = swz % 10;
  const int t_ = swz / 10;
  const int yb = t_ % 64;
  const int slot = t_ / 64;
  const int tid = threadIdx.x;
  const int w = tid >> 6, lane = tid & 63;
  int hrow0, rowlim;
  int tokq[4];
  const int trbase = w * 8 + (lane >> 3);
  if (slot < NSH) {
    if (yb * 256 >= TOK) return;
    hrow0 = slot * TOK + yb * 256;
    rowlim = 256;
#pragma unroll
    for (int q = 0; q < 4; ++q) tokq[q] = yb * 256 + q * 64 + trbase;
  } else {
    const int e = slot - NSH;
    const int cp = cpad[e];
    if (yb * 256 >= cp) return;
    const int base = roff[e];
    hrow0 = 2 * TOK + base + yb * 256;
    rowlim = cp - yb * 256; if (rowlim > 256) rowlim = 256;
#pragma unroll
    for (int q = 0; q < 4; ++q) tokq[q] = glist[base + yb * 256 + q * 64 + trbase];
  }
  const int srcoff = ((lane & 7) * 16) ^ (((lane >> 4) & 1) << 4) ^ (((lane >> 5) & 1) << 5) ^ ((w & 1) << 6);
  const char* aptr[4];
#pragma unroll
  for (int q = 0; q < 4; ++q) aptr[q] = (const char*)xb + (size_t)tokq[q] * 2048 + srcoff;
  const char* w13s = (const char*)w13b + (size_t)slot * 2560 * 2048;
  const int crow0 = (w >> 2) * 64 + (w & 3) * 8 + (lane >> 3);
  const char* bptr[2];
#pragma unroll
  for (int nq = 0; nq < 2; ++nq)
    bptr[nq] = w13s + (size_t)(bx * 256 + crow0 + nq * 32) * 2048 + srcoff;
  const int dA = (w * 8) * 128;
  const int dB = 32768 + (((w >> 2) * 64 + (w & 3) * 8) * 128);

#define STA(BB, MH, TT) do {                               \
    char* _d = smem + (BB) + dA + (MH) * 8192;             \
    gl_lds16(aptr[MH] + (TT) * 128, _d);                   \
    gl_lds16(aptr[(MH) + 2] + (TT) * 128, _d + 16384);     \
  } while (0)
#define STB(BB, NQ, TT) do {                               \
    char* _d = smem + (BB) + dB + (NQ) * 4096;             \
    gl_lds16(bptr[NQ] + (TT) * 128, _d);                   \
    gl_lds16(bptr[NQ] + 262144 + (TT) * 128, _d + 16384);  \
  } while (0)

  const int lr = lane & 15, lq = lane >> 4;
  const int kswz = (((lr >> 1) & 1) << 4) | (((lr >> 2) & 1) << 5) | (((lr >> 3) & 1) << 6);
  const int wm = w >> 2, wn = w & 3;
  const int aoffb = (wm * 128 + lr) * 128 + lq * 16;
  const int boffb = 32768 + (wn * 64 + lr) * 128 + lq * 16;

#define RD_A(BB, MH) do {                                                                            \
    _Pragma("unroll")                                                                                \
    for (int mf = 0; mf < 4; ++mf)                                                                   \
      _Pragma("unroll")                                                                              \
      for (int ks = 0; ks < 2; ++ks)                                                                 \
        areg[mf][ks] = *(const s16x8*)(smem + (((BB) + aoffb + (MH) * 8192 + mf * 2048 + ks * 64) ^ kswz)); \
  } while (0)
#define RD_B(BB, NQ, RG) do {                                                                        \
    _Pragma("unroll")                                                                                \
    for (int nf = 0; nf < 2; ++nf)                                                                   \
      _Pragma("unroll")                                                                              \
      for (int ks = 0; ks < 2; ++ks)                                                                 \
        RG[nf][ks] = *(const s16x8*)(smem + (((BB) + boffb + (NQ) * 4096 + nf * 2048 + ks * 64) ^ kswz)); \
  } while (0)
#define MFMA16(MH, RG, NQ) do {                                                                      \
    __builtin_amdgcn_s_setprio(1);                                                                   \
    _Pragma("unroll")                                                                                \
    for (int mf = 0; mf < 4; ++mf)                                                                   \
      _Pragma("unroll")                                                                              \
      for (int nf = 0; nf < 2; ++nf)                                                                 \
        _Pragma("unroll")                                                                            \
        for (int ks = 0; ks < 2; ++ks)                                                               \
          acc[(MH) * 4 + mf][(NQ) * 2 + nf] = __builtin_amdgcn_mfma_f32_16x16x32_bf16(               \
              areg[mf][ks], RG[nf][ks], acc[(MH) * 4 + mf][(NQ) * 2 + nf], 0, 0, 0);                 \
    __builtin_amdgcn_s_setprio(0);                                                                   \
  } while (0)
#define VMW(N) asm volatile("s_waitcnt vmcnt(" #N ")" ::: "memory")
#define BARR() __builtin_amdgcn_s_barrier()
#define LGKM0() asm volatile("s_waitcnt lgkmcnt(0)" ::: "memory")

  STA(0, 0, 0); STB(0, 0, 0); STA(0, 1, 0); STB(0, 1, 0);
  STA(65536, 0, 1); STB(65536, 0, 1);
  VMW(8);
  BARR();

  f32x4 acc[8][4] = {};
  for (int j = 0; j < G1_NT; ++j) {
    const int bufb = (j & 1) << 16;
    const int bufo = bufb ^ 65536;
    const int t1 = (j + 1 < G1_NT) ? j + 1 : G1_NT - 1;
    const int t2 = (j + 2 < G1_NT) ? j + 2 : G1_NT - 1;
    s16x8 areg[4][2];
    s16x8 breg0[2][2], breg1[2][2];
    RD_A(bufb, 0);
    RD_B(bufb, 0, breg0);
    STA(bufo, 1, t1);
    VMW(6);
    BARR(); LGKM0();
    MFMA16(0, breg0, 0);
    BARR();
    RD_B(bufb, 1, breg1);
    STB(bufo, 1, t1);
    BARR(); LGKM0();
    MFMA16(0, breg1, 1);
    BARR();
    RD_A(bufb, 1);
    STA(bufb, 0, t2);
    BARR(); LGKM0();
    MFMA16(1, breg1, 1);
    BARR();
    STB(bufb, 0, t2);
    VMW(8);
    BARR();
    MFMA16(1, breg0, 0);
    BARR();
  }
#undef STA
#undef STB

  asm volatile("s_waitcnt vmcnt(0)" ::: "memory");
  // epilogue: silu(w1col)*w3col -> h (bf16)
#pragma unroll
  for (int m = 0; m < 8; ++m) {
    const int lrow0 = wm * 128 + (m >> 2) * 64 + (m & 3) * 16 + lq * 4;
#pragma unroll
    for (int p = 0; p < 2; ++p) {
      f32x4 a1 = acc[m][2 * p];
      f32x4 a3 = acc[m][2 * p + 1];
      const int hc = (bx * 8 + wn * 2 + p) * 16 + lr;
#pragma unroll
      for (int r = 0; r < 4; ++r) {
        const int lrow = lrow0 + r;
        if (lrow < rowlim) {
          float u = a1[r];
          float hv = (u / (1.f + __expf(-u))) * a3[r];
          h[(size_t)(hrow0 + lrow) * HID + hc] = f2bf(hv);
        }
      }
    }
  }
#undef RD_A
#undef RD_B
#undef MFMA16
#undef VMW
#undef BARR
#undef LGKM0
}

// ---------------- GEMM2 grouped, same 4-phase 256x256x64 structure ----------------
// grp 0: shared, A = [h0|h1] K=2560 concat, B = [W2_0|W2_1], out = 0.5*acc (f32, full overwrite)
// grp 1..8: routed expert e, A = h routed rows, B = w2b[NSH+e], ro = bf16 (rowlim-guarded)
__global__ __launch_bounds__(512, 2) void k_gemm2g(const unsigned short* __restrict__ h,
                                                   const unsigned short* __restrict__ w2b,
                                                   const int* __restrict__ roff,
                                                   const int* __restrict__ cpad,
                                                   float* __restrict__ out,
                                                   unsigned short* __restrict__ ro) {
  extern __shared__ __align__(16) char smem[];
  const int grp = blockIdx.z, bx = blockIdx.x, yb = blockIdx.y;
  const int tid = threadIdx.x;
  const int w = tid >> 6, lane = tid & 63;
  const int trbase = w * 8 + (lane >> 3);
  int nt, rowlim, base = 0;
  size_t arow0, arow1;
  if (grp == 0) {
    if (yb * 256 >= TOK) return;
    nt = 40; rowlim = 256;
    arow0 = (size_t)(yb * 256);
    arow1 = (size_t)(TOK + yb * 256);
  } else {
    const int e = grp - 1;
    const int cp = cpad[e];
    if (yb * 256 >= cp) return;
    base = roff[e];
    nt = 20;
    rowlim = cp - yb * 256; if (rowlim > 256) rowlim = 256;
    arow0 = (size_t)(2 * TOK + base + yb * 256);
    arow1 = arow0;
  }
  const int srcoff = ((lane & 7) * 16) ^ (((lane >> 4) & 1) << 4) ^ (((lane >> 5) & 1) << 5) ^ ((w & 1) << 6);
  const char* aptr0[4];
  const char* aptr1[4];
#pragma unroll
  for (int q = 0; q < 4; ++q) {
    int rq = q * 64 + trbase;
    if (grp != 0 && rq >= rowlim) rq = 0;   // clamp: discarded rows read row 0 (no h overrun)
    aptr0[q] = (const char*)h + (arow0 + rq) * 2560 + srcoff;
    aptr1[q] = (const char*)h + (arow1 + rq) * 2560 + srcoff;
  }
  const int crow0 = (w >> 2) * 64 + (w & 3) * 8 + (lane >> 3);
  const char* bptr0[2];
  const char* bptr1[2];
#pragma unroll
  for (int nq = 0; nq < 2; ++nq) {
    const int bn = bx * 256 + crow0 + nq * 32;
    if (grp == 0) {
      bptr0[nq] = (const char*)w2b + (size_t)bn * 2560 + srcoff;                    // slot 0
      bptr1[nq] = (const char*)w2b + (size_t)(1024 + bn) * 2560 + srcoff;           // slot 1
    } else {
      bptr0[nq] = (const char*)w2b + (size_t)((NSH + grp - 1) * 1024 + bn) * 2560 + srcoff;
      bptr1[nq] = bptr0[nq];
    }
  }
  const int dA = (w * 8) * 128;
  const int dB = 32768 + (((w >> 2) * 64 + (w & 3) * 8) * 128);

#define ASRC(Q, TT) ((TT) < 20 ? aptr0[Q] + (TT) * 128 : aptr1[Q] + ((TT) - 20) * 128)
#define BSRC(NQ, TT) ((TT) < 20 ? bptr0[NQ] + (TT) * 128 : bptr1[NQ] + ((TT) - 20) * 128)
#define STA(BB, MH, TT) do {                               \
    char* _d = smem + (BB) + dA + (MH) * 8192;             \
    gl_lds16(ASRC(MH, TT), _d);                            \
    gl_lds16(ASRC((MH) + 2, TT), _d + 16384);              \
  } while (0)
#define STB(BB, NQ, TT) do {                               \
    char* _d = smem + (BB) + dB + (NQ) * 4096;             \
    gl_lds16(BSRC(NQ, TT), _d);                            \
    gl_lds16(BSRC(NQ, TT) + (size_t)128 * 2560, _d + 16384); \
  } while (0)

  const int lr = lane & 15, lq = lane >> 4;
  const int kswz = (((lr >> 1) & 1) << 4) | (((lr >> 2) & 1) << 5) | (((lr >> 3) & 1) << 6);
  const int wm = w >> 2, wn = w & 3;
  const int aoffb = (wm * 128 + lr) * 128 + lq * 16;
  const int boffb = 32768 + (wn * 64 + lr) * 128 + lq * 16;

#define RD_A(BB, MH) do {                                                                            \
    _Pragma("unroll")                                                                                \
    for (int mf = 0; mf < 4; ++mf)                                                                   \
      _Pragma("unroll")                                                                              \
      for (int ks = 0; ks < 2; ++ks)                                                                 \
        areg[mf][ks] = *(const s16x8*)(smem + (((BB) + aoffb + (MH) * 8192 + mf * 2048 + ks * 64) ^ kswz)); \
  } while (0)
#define RD_B(BB, NQ, RG) do {                                                                        \
    _Pragma("unroll")                                                                                \
    for (int nf = 0; nf < 2; ++nf)                                                                   \
      _Pragma("unroll")                                                                              \
      for (int ks = 0; ks < 2; ++ks)                                                                 \
        RG[nf][ks] = *(const s16x8*)(smem + (((BB) + boffb + (NQ) * 4096 + nf * 2048 + ks * 64) ^ kswz)); \
  } while (0)
#define MFMA16(MH, RG, NQ) do {                                                                      \
    __builtin_amdgcn_s_setprio(1);                                                                   \
    _Pragma("unroll")                                                                                \
    for (int mf = 0; mf < 4; ++mf)                                                                   \
      _Pragma("unroll")                                                                              \
      for (int nf = 0; nf < 2; ++nf)                                                                 \
        _Pragma("unroll")                                                                            \
        for (int ks = 0; ks < 2; ++ks)                                                               \
          acc[(MH) * 4 + mf][(NQ) * 2 + nf] = __builtin_amdgcn_mfma_f32_16x16x32_bf16(               \
              areg[mf][ks], RG[nf][ks], acc[(MH) * 4 + mf][(NQ) * 2 + nf], 0, 0, 0);                 \
    __builtin_amdgcn_s_setprio(0);                                                                   \
  } while (0)
#define VMW(N) asm volatile("s_waitcnt vmcnt(" #N ")" ::: "memory")
#define BARR() __builtin_amdgcn_s_barrier()
#define LGKM0() asm volatile("s_waitcnt lgkmcnt(0)" ::: "memory")

  STA(0, 0, 0); STB(0, 0, 0); STA(0, 1, 0); STB(0, 1, 0);
  STA(65536, 0, 1); STB(65536, 0, 1);
  VMW(8);
  BARR();

  f32x4 acc[8][4] = {};
  for (int j = 0; j < nt; ++j) {
    const int bufb = (j & 1) << 16;
    const int bufo = bufb ^ 65536;
    const int t1 = (j + 1 < nt) ? j + 1 : nt - 1;
    const int t2 = (j + 2 < nt) ? j + 2 : nt - 1;
    s16x8 areg[4][2];
    s16x8 breg0[2][2], breg1[2][2];
    RD_A(bufb, 0);
    RD_B(bufb, 0, breg0);
    STA(bufo, 1, t1);
    VMW(6);
    BARR(); LGKM0();
    MFMA16(0, breg0, 0);
    BARR();
    RD_B(bufb, 1, breg1);
    STB(bufo, 1, t1);
    BARR(); LGKM0();
    MFMA16(0, breg1, 1);
    BARR();
    RD_A(bufb, 1);
    STA(bufb, 0, t2);
    BARR(); LGKM0();
    MFMA16(1, breg1, 1);
    BARR();
    STB(bufb, 0, t2);
    VMW(8);
    BARR();
    MFMA16(1, breg0, 0);
    BARR();
  }
#undef STA
#undef STB
#undef ASRC
#undef BSRC

  asm volatile("s_waitcnt vmcnt(0)" ::: "memory");
  if (grp == 0) {
#pragma unroll
    for (int m = 0; m < 8; ++m) {
      const int lrow0 = wm * 128 + (m >> 2) * 64 + (m & 3) * 16 + lq * 4;
#pragma unroll
      for (int nf = 0; nf < 4; ++nf) {
        const int col = bx * 256 + wn * 64 + nf * 16 + lr;
#pragma unroll
        for (int r = 0; r < 4; ++r)
          out[(size_t)(yb * 256 + lrow0 + r) * DIMN + col] = 0.5f * acc[m][nf][r];
      }
    }
  } else {
#pragma unroll
    for (int m = 0; m < 8; ++m) {
      const int lrow0 = wm * 128 + (m >> 2) * 64 + (m & 3) * 16 + lq * 4;
#pragma unroll
      for (int r = 0; r < 4; ++r) {
        const int lrow = lrow0 + r;
        if (lrow < rowlim) {
          const size_t g = (size_t)(base + yb * 256 + lrow);
#pragma unroll
          for (int nf = 0; nf < 4; ++nf) {
            const int col = bx * 256 + wn * 64 + nf * 16 + lr;
            ro[g * DIMN + col] = f2bf(acc[m][nf][r]);
          }
        }
      }
    }
  }
#undef RD_A
#undef RD_B
#undef MFMA16
#undef VMW
#undef BARR
#undef LGKM0
}

// ---------------- combine: out[t] += w0*ro[g0] + w1*ro[g1] ----------------
__global__ __launch_bounds__(256) void k_combine(const unsigned short* __restrict__ ro,
                                                 const int* __restrict__ pos,
                                                 const float* __restrict__ tw,
                                                 float* __restrict__ out) {
  const int t = blockIdx.x;
  const int g0 = pos[2 * t], g1 = pos[2 * t + 1];
  const float w0 = tw[2 * t], w1 = tw[2 * t + 1];
  const int c = threadIdx.x * 4;
  ushort4 r0 = *(const ushort4*)(ro + (size_t)g0 * DIMN + c);
  ushort4 r1 = *(const ushort4*)(ro + (size_t)g1 * DIMN + c);
  float4 o = *(float4*)(out + (size_t)t * DIMN + c);
  o.x += w0 * bf2f(r0.x) + w1 * bf2f(r1.x);
  o.y += w0 * bf2f(r0.y) + w1 * bf2f(r1.y);
  o.z += w0 * bf2f(r0.z) + w1 * bf2f(r1.z);
  o.w += w0 * bf2f(r0.w) + w1 * bf2f(r1.w);
  *(float4*)(out + (size_t)t * DIMN + c) = o;
}

// ---------------- ws layout ----------------
static const size_t OFF_XB    = 0;
static const size_t OFF_W13   = OFF_XB + (size_t)TOK * DIMN * 2;
static const size_t OFF_W2    = OFF_W13 + (size_t)NSLOT * 2560 * DIMN * 2;
static const size_t OFF_H     = OFF_W2 + (size_t)NSLOT * DIMN * HID * 2;
// ro (RCAPG x DIMN bf16 = 36.2 MB) aliases w13b (52.4 MB): w13b dead after gemm1,
// gemm2g (ro writer) runs strictly after gemm1 in stream order.
static const size_t OFF_RO    = OFF_W13;
static const size_t OFF_GLIST = OFF_H + (size_t)(2 * TOK + RCAP) * HID * 2;
static const size_t OFF_POS   = OFF_GLIST + (size_t)RCAPG * 4;
static const size_t OFF_TIDX  = OFF_POS + (size_t)TOK * 2 * 4;
static const size_t OFF_TW    = OFF_TIDX + (size_t)TOK * 2 * 4;
static const size_t OFF_ENTP  = OFF_TW + (size_t)TOK * 2 * 4;
static const size_t OFF_CNT   = OFF_ENTP + (size_t)NGATE * 4;
static const size_t OFF_CNT2  = OFF_CNT + 32;
static const size_t OFF_ROFF  = OFF_CNT2 + 32;
static const size_t OFF_CPAD  = OFF_ROFF + 32;

extern "C" void kernel_launch(void* const* d_in, const int* in_sizes, int n_in,
                              void* d_out, int out_size, void* d_ws, size_t ws_size,
                              hipStream_t stream) {
  const float* x    = (const float*)d_in[0];
  const float* emb  = (const float*)d_in[1];
  const float* bias = (const float*)d_in[2];
  const float* w1   = (const float*)d_in[3];
  const float* w2   = (const float*)d_in[4];
  const float* w3   = (const float*)d_in[5];
  const float* sw1  = (const float*)d_in[6];
  const float* sw2  = (const float*)d_in[7];
  const float* sw3  = (const float*)d_in[8];
  float* out = (float*)d_out;
  char* ws = (char*)d_ws;
  unsigned short* xb   = (unsigned short*)(ws + OFF_XB);
  unsigned short* w13b = (unsigned short*)(ws + OFF_W13);
  unsigned short* w2b  = (unsigned short*)(ws + OFF_W2);
  unsigned short* h    = (unsigned short*)(ws + OFF_H);
  unsigned short* ro   = (unsigned short*)(ws + OFF_RO);
  int*   glist = (int*)(ws + OFF_GLIST);
  int*   pos   = (int*)(ws + OFF_POS);
  int*   tidx  = (int*)(ws + OFF_TIDX);
  float* tw    = (float*)(ws + OFF_TW);
  float* entp  = (float*)(ws + OFF_ENTP);
  int*   cnt   = (int*)(ws + OFF_CNT);
  int*   cnt2  = (int*)(ws + OFF_CNT2);
  int*   roff  = (int*)(ws + OFF_ROFF);
  int*   cpad  = (int*)(ws + OFF_CPAD);

  hipFuncSetAttribute((const void*)k_gemm1_8ph, hipFuncAttributeMaxDynamicSharedMemorySize, 131072);
  hipFuncSetAttribute((const void*)k_gemm2g, hipFuncAttributeMaxDynamicSharedMemorySize, 131072);

  k_zero<<<(RCAPG + 255) / 256, 256, 0, stream>>>(glist, cnt, cnt2);
  k_cvt_x<<<(TOK * DIMN / 4) / 256, 256, 0, stream>>>(x, xb);
  k_cvt_w<<<dim3(2560 + DIMN, NSLOT), 256, 0, stream>>>(w1, w3, sw1, sw3, w2, sw2, w13b, w2b);
  k_gate<<<NGATE, 256, 0, stream>>>(x, emb, bias, tidx, tw, entp);
  k_count<<<TOK / 256, 256, 0, stream>>>(tidx, cnt);
  k_offsets<<<1, 256, 0, stream>>>(cnt, roff, cpad, entp, out + (size_t)TOK * DIMN);
  k_scatter<<<TOK / 256, 256, 0, stream>>>(tidx, roff, cnt2, glist, pos);
  k_gemm1_8ph<<<dim3(10, 64, 10), 512, 131072, stream>>>(xb, w13b, h, glist, roff, cpad);
  k_gemm2g<<<dim3(DIMN / 256, 64, 1 + NEXP), 512, 131072, stream>>>(h, w2b, roff, cpad, out, ro);
  k_combine<<<TOK, 256, 0, stream>>>(ro, pos, tw, out);
}

// Round 7
// 427.243 us; speedup vs baseline: 2.0177x; 1.6152x over previous
//
#include <hip/hip_runtime.h>
#include <math.h>

#define TOK 8192
#define DIMN 1024
#define HID 1280
#define NEXP 8
#define NSH 2
#define NSLOT 10
#define RCAP 17408          // 16384 + 8*128 max padding
#define RCAPG (RCAP + 256)  // glist slack for 256-row tiles
#define G1_NT (DIMN / 64)   // 16 K-tiles of 64 for gemm1
#define NGATE (TOK / 4)     // gate blocks

typedef short s16x8 __attribute__((ext_vector_type(8)));
typedef float f32x4 __attribute__((ext_vector_type(4)));

// f32 -> bf16 RNE
__device__ __forceinline__ unsigned short f2bf(float f) {
  unsigned u = __float_as_uint(f);
  u += 0x7fffu + ((u >> 16) & 1u);
  return (unsigned short)(u >> 16);
}
__device__ __forceinline__ float bf2f(unsigned short u) {
  return __uint_as_float((unsigned)u << 16);
}

__device__ __forceinline__ void gl_lds16(const void* g, void* l) {
  typedef __attribute__((address_space(1))) const unsigned int guint;
  typedef __attribute__((address_space(3))) unsigned int luint;
  __builtin_amdgcn_global_load_lds((guint*)g, (luint*)l, 16, 0, 0);
}

// ---------------- init / zero ----------------
__global__ __launch_bounds__(256) void k_zero(int* __restrict__ glist,
                                              int* __restrict__ cnt, int* __restrict__ cnt2) {
  int i = blockIdx.x * 256 + threadIdx.x;
  if (i < RCAPG) glist[i] = 0;
  if (i < NEXP) { cnt[i] = 0; cnt2[i] = 0; }
}

// ---------------- converts ----------------
__global__ __launch_bounds__(256) void k_cvt_x(const float* __restrict__ x,
                                               unsigned short* __restrict__ xb) {
  int i = blockIdx.x * 256 + threadIdx.x;
  float4 v = ((const float4*)x)[i];
  ushort4 o;
  o.x = f2bf(v.x); o.y = f2bf(v.y); o.z = f2bf(v.z); o.w = f2bf(v.w);
  ((ushort4*)xb)[i] = o;
}

// merged weight convert: r<2560 -> w13b row (interleaved w1/w3 16-col groups); else w2b row
__global__ __launch_bounds__(256) void k_cvt_w(const float* __restrict__ w1, const float* __restrict__ w3,
                                               const float* __restrict__ sw1, const float* __restrict__ sw3,
                                               const float* __restrict__ w2, const float* __restrict__ sw2,
                                               unsigned short* __restrict__ w13b,
                                               unsigned short* __restrict__ w2b) {
  const int r = blockIdx.x;
  const int s = blockIdx.y;
  if (r < 2560) {
    const int which = (r >> 4) & 1;
    const int srow = ((r >> 5) << 4) + (r & 15);
    const float* src;
    if (s < NSH) src = (which ? sw3 : sw1) + ((size_t)s * HID + srow) * DIMN;
    else         src = (which ? w3 : w1) + ((size_t)(s - NSH) * HID + srow) * DIMN;
    unsigned short* dst = w13b + ((size_t)s * 2560 + r) * DIMN;
    int c = threadIdx.x * 4;
    float4 v = *(const float4*)(src + c);
    ushort4 o;
    o.x = f2bf(v.x); o.y = f2bf(v.y); o.z = f2bf(v.z); o.w = f2bf(v.w);
    *(ushort4*)(dst + c) = o;
  } else {
    const int d = r - 2560;
    const float* src = (s < NSH) ? sw2 + ((size_t)s * DIMN + d) * HID
                                 : w2 + ((size_t)(s - NSH) * DIMN + d) * HID;
    unsigned short* dst = w2b + ((size_t)s * DIMN + d) * HID;
    for (int c = threadIdx.x * 4; c < HID; c += 1024) {
      float4 v = *(const float4*)(src + c);
      ushort4 o;
      o.x = f2bf(v.x); o.y = f2bf(v.y); o.z = f2bf(v.z); o.w = f2bf(v.w);
      *(ushort4*)(dst + c) = o;
    }
  }
}

// ---------------- gate (f32 semantics preserved EXACTLY; no global atomics) ----------------
__global__ __launch_bounds__(256) void k_gate(const float* __restrict__ x, const float* __restrict__ emb,
                                              const float* __restrict__ bias, int* __restrict__ tidx,
                                              float* __restrict__ tw, float* __restrict__ entp) {
  const int lane = threadIdx.x & 63;
  const int wv = threadIdx.x >> 6;
  const int t = blockIdx.x * 4 + wv;
  const float* xr = x + (size_t)t * DIMN;
  float acc[NEXP];
#pragma unroll
  for (int e = 0; e < NEXP; ++e) acc[e] = 0.0f;
  for (int i = 0; i < DIMN / 64; ++i) {
    float xv = xr[lane + 64 * i];
#pragma unroll
    for (int e = 0; e < NEXP; ++e)
      acc[e] = fmaf(xv, emb[e * DIMN + lane + 64 * i], acc[e]);
  }
#pragma unroll
  for (int e = 0; e < NEXP; ++e) {
#pragma unroll
    for (int off = 32; off > 0; off >>= 1) acc[e] += __shfl_xor(acc[e], off);
  }
  __shared__ float ebuf[4];
  if (lane == 0) {
    float s[NEXP];
#pragma unroll
    for (int e = 0; e < NEXP; ++e) s[e] = 1.0f / (1.0f + expf(-acc[e])) + bias[e];
    int i0 = 0;
    for (int e = 1; e < NEXP; ++e) if (s[e] > s[i0]) i0 = e;   // strict >: lowest index wins ties
    int i1 = -1;
    for (int e = 0; e < NEXP; ++e) {
      if (e == i0) continue;
      if (i1 < 0 || s[e] > s[i1]) i1 = e;
    }
    float v0 = s[i0], v1 = s[i1];
    float inv = 1.0f / (v0 + v1);
    float w0 = v0 * inv, w1 = v1 * inv;
    tidx[2 * t] = i0; tidx[2 * t + 1] = i1;
    tw[2 * t] = w0; tw[2 * t + 1] = w1;
    ebuf[wv] = -(w0 * logf(w0) + w1 * logf(w1));
  }
  __syncthreads();
  if (threadIdx.x == 0) entp[blockIdx.x] = ebuf[0] + ebuf[1] + ebuf[2] + ebuf[3];
}

// ---------------- count: LDS histogram, 8 global atomics per block ----------------
__global__ __launch_bounds__(256) void k_count(const int* __restrict__ tidx, int* __restrict__ cnt) {
  __shared__ int hist[NEXP];
  const int tid = threadIdx.x;
  if (tid < NEXP) hist[tid] = 0;
  __syncthreads();
  const int t = blockIdx.x * 256 + tid;
  atomicAdd(&hist[tidx[2 * t]], 1);
  atomicAdd(&hist[tidx[2 * t + 1]], 1);
  __syncthreads();
  if (tid < NEXP) atomicAdd(&cnt[tid], hist[tid]);
}

// ---------------- offsets + entropy reduce + tail finalize ----------------
__global__ __launch_bounds__(256) void k_offsets(const int* __restrict__ cnt, int* __restrict__ roff,
                                                 int* __restrict__ cpad, const float* __restrict__ entp,
                                                 float* __restrict__ out_tail) {
  __shared__ float red[256];
  float s = 0.f;
  for (int i = threadIdx.x; i < NGATE; i += 256) s += entp[i];
  red[threadIdx.x] = s;
  __syncthreads();
  for (int st = 128; st > 0; st >>= 1) {
    if (threadIdx.x < st) red[threadIdx.x] += red[threadIdx.x + st];
    __syncthreads();
  }
  if (threadIdx.x == 0) {
    int off = 0;
    for (int e = 0; e < NEXP; ++e) {
      roff[e] = off;
      int cp = (cnt[e] + 127) & ~127;
      cpad[e] = cp;
      off += cp;
    }
    out_tail[0] = 0.f;
    out_tail[1] = red[0] / (float)TOK;
  }
}

// ---------------- scatter: LDS histogram + one range-claim atomic per (block,expert) ----------------
__global__ __launch_bounds__(256) void k_scatter(const int* __restrict__ tidx,
                                                 const int* __restrict__ roff, int* __restrict__ cnt2,
                                                 int* __restrict__ glist, int* __restrict__ pos) {
  __shared__ int hist[NEXP], base[NEXP], cur[NEXP];
  const int tid = threadIdx.x;
  if (tid < NEXP) { hist[tid] = 0; cur[tid] = 0; }
  __syncthreads();
  const int t = blockIdx.x * 256 + tid;
  const int e0 = tidx[2 * t], e1 = tidx[2 * t + 1];
  atomicAdd(&hist[e0], 1);
  atomicAdd(&hist[e1], 1);
  __syncthreads();
  if (tid < NEXP) base[tid] = atomicAdd(&cnt2[tid], hist[tid]);
  __syncthreads();
  int p0 = atomicAdd(&cur[e0], 1);
  int g0 = roff[e0] + base[e0] + p0;
  glist[g0] = t; pos[2 * t] = g0;
  int p1 = atomicAdd(&cur[e1], 1);
  int g1 = roff[e1] + base[e1] + p1;
  glist[g1] = t; pos[2 * t + 1] = g1;
}

// ---------------- GEMM1, 4-phase 256x256x64, LINEAR block mapping ----------------
// Round-7: T1 chunk swizzle REVERTED — with ~60% early-return blocks the chunked
// mapping concentrates real work onto few XCDs (round 6: occupancy 19%->7%,
// 232->553us). Linear round-robin dispatch is the correct balancer for ragged grids.
__global__ __launch_bounds__(512, 2) void k_gemm1_8ph(const unsigned short* __restrict__ xb,
                                                      const unsigned short* __restrict__ w13b,
                                                      unsigned short* __restrict__ h,
                                                      const int* __restrict__ glist,
                                                      const int* __restrict__ roff,
                                                      const int* __restrict__ cpad) {
  extern __shared__ __align__(16) char smem[];
  const int slot = blockIdx.z, yb = blockIdx.y, bx = blockIdx.x;
  const int tid = threadIdx.x;
  const int w = tid >> 6, lane = tid & 63;
  int hrow0, rowlim;
  int tokq[4];
  const int trbase = w * 8 + (lane >> 3);
  if (slot < NSH) {
    hrow0 = slot * TOK + yb * 256;
    rowlim = 256;
#pragma unroll
    for (int q = 0; q < 4; ++q) tokq[q] = yb * 256 + q * 64 + trbase;
  } else {
    const int e = slot - NSH;
    const int cp = cpad[e];
    if (yb * 256 >= cp) return;
    const int base = roff[e];
    hrow0 = 2 * TOK + base + yb * 256;
    rowlim = cp - yb * 256; if (rowlim > 256) rowlim = 256;
#pragma unroll
    for (int q = 0; q < 4; ++q) tokq[q] = glist[base + yb * 256 + q * 64 + trbase];
  }
  const int srcoff = ((lane & 7) * 16) ^ (((lane >> 4) & 1) << 4) ^ (((lane >> 5) & 1) << 5) ^ ((w & 1) << 6);
  const char* aptr[4];
#pragma unroll
  for (int q = 0; q < 4; ++q) aptr[q] = (const char*)xb + (size_t)tokq[q] * 2048 + srcoff;
  const char* w13s = (const char*)w13b + (size_t)slot * 2560 * 2048;
  const int crow0 = (w >> 2) * 64 + (w & 3) * 8 + (lane >> 3);
  const char* bptr[2];
#pragma unroll
  for (int nq = 0; nq < 2; ++nq)
    bptr[nq] = w13s + (size_t)(bx * 256 + crow0 + nq * 32) * 2048 + srcoff;
  const int dA = (w * 8) * 128;
  const int dB = 32768 + (((w >> 2) * 64 + (w & 3) * 8) * 128);

#define STA(BB, MH, TT) do {                               \
    char* _d = smem + (BB) + dA + (MH) * 8192;             \
    gl_lds16(aptr[MH] + (TT) * 128, _d);                   \
    gl_lds16(aptr[(MH) + 2] + (TT) * 128, _d + 16384);     \
  } while (0)
#define STB(BB, NQ, TT) do {                               \
    char* _d = smem + (BB) + dB + (NQ) * 4096;             \
    gl_lds16(bptr[NQ] + (TT) * 128, _d);                   \
    gl_lds16(bptr[NQ] + 262144 + (TT) * 128, _d + 16384);  \
  } while (0)

  const int lr = lane & 15, lq = lane >> 4;
  const int kswz = (((lr >> 1) & 1) << 4) | (((lr >> 2) & 1) << 5) | (((lr >> 3) & 1) << 6);
  const int wm = w >> 2, wn = w & 3;
  const int aoffb = (wm * 128 + lr) * 128 + lq * 16;
  const int boffb = 32768 + (wn * 64 + lr) * 128 + lq * 16;

#define RD_A(BB, MH) do {                                                                            \
    _Pragma("unroll")                                                                                \
    for (int mf = 0; mf < 4; ++mf)                                                                   \
      _Pragma("unroll")                                                                              \
      for (int ks = 0; ks < 2; ++ks)                                                                 \
        areg[mf][ks] = *(const s16x8*)(smem + (((BB) + aoffb + (MH) * 8192 + mf * 2048 + ks * 64) ^ kswz)); \
  } while (0)
#define RD_B(BB, NQ, RG) do {                                                                        \
    _Pragma("unroll")                                                                                \
    for (int nf = 0; nf < 2; ++nf)                                                                   \
      _Pragma("unroll")                                                                              \
      for (int ks = 0; ks < 2; ++ks)                                                                 \
        RG[nf][ks] = *(const s16x8*)(smem + (((BB) + boffb + (NQ) * 4096 + nf * 2048 + ks * 64) ^ kswz)); \
  } while (0)
#define MFMA16(MH, RG, NQ) do {                                                                      \
    __builtin_amdgcn_s_setprio(1);                                                                   \
    _Pragma("unroll")                                                                                \
    for (int mf = 0; mf < 4; ++mf)                                                                   \
      _Pragma("unroll")                                                                              \
      for (int nf = 0; nf < 2; ++nf)                                                                 \
        _Pragma("unroll")                                                                            \
        for (int ks = 0; ks < 2; ++ks)                                                               \
          acc[(MH) * 4 + mf][(NQ) * 2 + nf] = __builtin_amdgcn_mfma_f32_16x16x32_bf16(               \
              areg[mf][ks], RG[nf][ks], acc[(MH) * 4 + mf][(NQ) * 2 + nf], 0, 0, 0);                 \
    __builtin_amdgcn_s_setprio(0);                                                                   \
  } while (0)
#define VMW(N) asm volatile("s_waitcnt vmcnt(" #N ")" ::: "memory")
#define BARR() __builtin_amdgcn_s_barrier()
#define LGKM0() asm volatile("s_waitcnt lgkmcnt(0)" ::: "memory")

  STA(0, 0, 0); STB(0, 0, 0); STA(0, 1, 0); STB(0, 1, 0);
  STA(65536, 0, 1); STB(65536, 0, 1);
  VMW(8);
  BARR();

  f32x4 acc[8][4] = {};
  for (int j = 0; j < G1_NT; ++j) {
    const int bufb = (j & 1) << 16;
    const int bufo = bufb ^ 65536;
    const int t1 = (j + 1 < G1_NT) ? j + 1 : G1_NT - 1;
    const int t2 = (j + 2 < G1_NT) ? j + 2 : G1_NT - 1;
    s16x8 areg[4][2];
    s16x8 breg0[2][2], breg1[2][2];
    RD_A(bufb, 0);
    RD_B(bufb, 0, breg0);
    STA(bufo, 1, t1);
    VMW(6);
    BARR(); LGKM0();
    MFMA16(0, breg0, 0);
    BARR();
    RD_B(bufb, 1, breg1);
    STB(bufo, 1, t1);
    BARR(); LGKM0();
    MFMA16(0, breg1, 1);
    BARR();
    RD_A(bufb, 1);
    STA(bufb, 0, t2);
    BARR(); LGKM0();
    MFMA16(1, breg1, 1);
    BARR();
    STB(bufb, 0, t2);
    VMW(8);
    BARR();
    MFMA16(1, breg0, 0);
    BARR();
  }
#undef STA
#undef STB

  asm volatile("s_waitcnt vmcnt(0)" ::: "memory");
  // epilogue: silu(w1col)*w3col -> h (bf16)
#pragma unroll
  for (int m = 0; m < 8; ++m) {
    const int lrow0 = wm * 128 + (m >> 2) * 64 + (m & 3) * 16 + lq * 4;
#pragma unroll
    for (int p = 0; p < 2; ++p) {
      f32x4 a1 = acc[m][2 * p];
      f32x4 a3 = acc[m][2 * p + 1];
      const int hc = (bx * 8 + wn * 2 + p) * 16 + lr;
#pragma unroll
      for (int r = 0; r < 4; ++r) {
        const int lrow = lrow0 + r;
        if (lrow < rowlim) {
          float u = a1[r];
          float hv = (u / (1.f + __expf(-u))) * a3[r];
          h[(size_t)(hrow0 + lrow) * HID + hc] = f2bf(hv);
        }
      }
    }
  }
#undef RD_A
#undef RD_B
#undef MFMA16
#undef VMW
#undef BARR
#undef LGKM0
}

// ---------------- GEMM2 grouped, same 4-phase 256x256x64 structure ----------------
// grp 0: shared, A = [h0|h1] K=2560 concat, B = [W2_0|W2_1], out = 0.5*acc (f32, full overwrite)
// grp 1..8: routed expert e, A = h routed rows, B = w2b[NSH+e], ro = bf16 (rowlim-guarded)
__global__ __launch_bounds__(512, 2) void k_gemm2g(const unsigned short* __restrict__ h,
                                                   const unsigned short* __restrict__ w2b,
                                                   const int* __restrict__ roff,
                                                   const int* __restrict__ cpad,
                                                   float* __restrict__ out,
                                                   unsigned short* __restrict__ ro) {
  extern __shared__ __align__(16) char smem[];
  const int grp = blockIdx.z, bx = blockIdx.x, yb = blockIdx.y;
  const int tid = threadIdx.x;
  const int w = tid >> 6, lane = tid & 63;
  const int trbase = w * 8 + (lane >> 3);
  int nt, rowlim, base = 0;
  size_t arow0, arow1;
  if (grp == 0) {
    if (yb * 256 >= TOK) return;
    nt = 40; rowlim = 256;
    arow0 = (size_t)(yb * 256);
    arow1 = (size_t)(TOK + yb * 256);
  } else {
    const int e = grp - 1;
    const int cp = cpad[e];
    if (yb * 256 >= cp) return;
    base = roff[e];
    nt = 20;
    rowlim = cp - yb * 256; if (rowlim > 256) rowlim = 256;
    arow0 = (size_t)(2 * TOK + base + yb * 256);
    arow1 = arow0;
  }
  const int srcoff = ((lane & 7) * 16) ^ (((lane >> 4) & 1) << 4) ^ (((lane >> 5) & 1) << 5) ^ ((w & 1) << 6);
  const char* aptr0[4];
  const char* aptr1[4];
#pragma unroll
  for (int q = 0; q < 4; ++q) {
    int rq = q * 64 + trbase;
    if (grp != 0 && rq >= rowlim) rq = 0;   // clamp: discarded rows read row 0 (no h overrun)
    aptr0[q] = (const char*)h + (arow0 + rq) * 2560 + srcoff;
    aptr1[q] = (const char*)h + (arow1 + rq) * 2560 + srcoff;
  }
  const int crow0 = (w >> 2) * 64 + (w & 3) * 8 + (lane >> 3);
  const char* bptr0[2];
  const char* bptr1[2];
#pragma unroll
  for (int nq = 0; nq < 2; ++nq) {
    const int bn = bx * 256 + crow0 + nq * 32;
    if (grp == 0) {
      bptr0[nq] = (const char*)w2b + (size_t)bn * 2560 + srcoff;                    // slot 0
      bptr1[nq] = (const char*)w2b + (size_t)(1024 + bn) * 2560 + srcoff;           // slot 1
    } else {
      bptr0[nq] = (const char*)w2b + (size_t)((NSH + grp - 1) * 1024 + bn) * 2560 + srcoff;
      bptr1[nq] = bptr0[nq];
    }
  }
  const int dA = (w * 8) * 128;
  const int dB = 32768 + (((w >> 2) * 64 + (w & 3) * 8) * 128);

#define ASRC(Q, TT) ((TT) < 20 ? aptr0[Q] + (TT) * 128 : aptr1[Q] + ((TT) - 20) * 128)
#define BSRC(NQ, TT) ((TT) < 20 ? bptr0[NQ] + (TT) * 128 : bptr1[NQ] + ((TT) - 20) * 128)
#define STA(BB, MH, TT) do {                               \
    char* _d = smem + (BB) + dA + (MH) * 8192;             \
    gl_lds16(ASRC(MH, TT), _d);                            \
    gl_lds16(ASRC((MH) + 2, TT), _d + 16384);              \
  } while (0)
#define STB(BB, NQ, TT) do {                               \
    char* _d = smem + (BB) + dB + (NQ) * 4096;             \
    gl_lds16(BSRC(NQ, TT), _d);                            \
    gl_lds16(BSRC(NQ, TT) + (size_t)128 * 2560, _d + 16384); \
  } while (0)

  const int lr = lane & 15, lq = lane >> 4;
  const int kswz = (((lr >> 1) & 1) << 4) | (((lr >> 2) & 1) << 5) | (((lr >> 3) & 1) << 6);
  const int wm = w >> 2, wn = w & 3;
  const int aoffb = (wm * 128 + lr) * 128 + lq * 16;
  const int boffb = 32768 + (wn * 64 + lr) * 128 + lq * 16;

#define RD_A(BB, MH) do {                                                                            \
    _Pragma("unroll")                                                                                \
    for (int mf = 0; mf < 4; ++mf)                                                                   \
      _Pragma("unroll")                                                                              \
      for (int ks = 0; ks < 2; ++ks)                                                                 \
        areg[mf][ks] = *(const s16x8*)(smem + (((BB) + aoffb + (MH) * 8192 + mf * 2048 + ks * 64) ^ kswz)); \
  } while (0)
#define RD_B(BB, NQ, RG) do {                                                                        \
    _Pragma("unroll")                                                                                \
    for (int nf = 0; nf < 2; ++nf)                                                                   \
      _Pragma("unroll")                                                                              \
      for (int ks = 0; ks < 2; ++ks)                                                                 \
        RG[nf][ks] = *(const s16x8*)(smem + (((BB) + boffb + (NQ) * 4096 + nf * 2048 + ks * 64) ^ kswz)); \
  } while (0)
#define MFMA16(MH, RG, NQ) do {                                                                      \
    __builtin_amdgcn_s_setprio(1);                                                                   \
    _Pragma("unroll")                                                                                \
    for (int mf = 0; mf < 4; ++mf)                                                                   \
      _Pragma("unroll")                                                                              \
      for (int nf = 0; nf < 2; ++nf)                                                                 \
        _Pragma("unroll")                                                                            \
        for (int ks = 0; ks < 2; ++ks)                                                               \
          acc[(MH) * 4 + mf][(NQ) * 2 + nf] = __builtin_amdgcn_mfma_f32_16x16x32_bf16(               \
              areg[mf][ks], RG[nf][ks], acc[(MH) * 4 + mf][(NQ) * 2 + nf], 0, 0, 0);                 \
    __builtin_amdgcn_s_setprio(0);                                                                   \
  } while (0)
#define VMW(N) asm volatile("s_waitcnt vmcnt(" #N ")" ::: "memory")
#define BARR() __builtin_amdgcn_s_barrier()
#define LGKM0() asm volatile("s_waitcnt lgkmcnt(0)" ::: "memory")

  STA(0, 0, 0); STB(0, 0, 0); STA(0, 1, 0); STB(0, 1, 0);
  STA(65536, 0, 1); STB(65536, 0, 1);
  VMW(8);
  BARR();

  f32x4 acc[8][4] = {};
  for (int j = 0; j < nt; ++j) {
    const int bufb = (j & 1) << 16;
    const int bufo = bufb ^ 65536;
    const int t1 = (j + 1 < nt) ? j + 1 : nt - 1;
    const int t2 = (j + 2 < nt) ? j + 2 : nt - 1;
    s16x8 areg[4][2];
    s16x8 breg0[2][2], breg1[2][2];
    RD_A(bufb, 0);
    RD_B(bufb, 0, breg0);
    STA(bufo, 1, t1);
    VMW(6);
    BARR(); LGKM0();
    MFMA16(0, breg0, 0);
    BARR();
    RD_B(bufb, 1, breg1);
    STB(bufo, 1, t1);
    BARR(); LGKM0();
    MFMA16(0, breg1, 1);
    BARR();
    RD_A(bufb, 1);
    STA(bufb, 0, t2);
    BARR(); LGKM0();
    MFMA16(1, breg1, 1);
    BARR();
    STB(bufb, 0, t2);
    VMW(8);
    BARR();
    MFMA16(1, breg0, 0);
    BARR();
  }
#undef STA
#undef STB
#undef ASRC
#undef BSRC

  asm volatile("s_waitcnt vmcnt(0)" ::: "memory");
  if (grp == 0) {
#pragma unroll
    for (int m = 0; m < 8; ++m) {
      const int lrow0 = wm * 128 + (m >> 2) * 64 + (m & 3) * 16 + lq * 4;
#pragma unroll
      for (int nf = 0; nf < 4; ++nf) {
        const int col = bx * 256 + wn * 64 + nf * 16 + lr;
#pragma unroll
        for (int r = 0; r < 4; ++r)
          out[(size_t)(yb * 256 + lrow0 + r) * DIMN + col] = 0.5f * acc[m][nf][r];
      }
    }
  } else {
#pragma unroll
    for (int m = 0; m < 8; ++m) {
      const int lrow0 = wm * 128 + (m >> 2) * 64 + (m & 3) * 16 + lq * 4;
#pragma unroll
      for (int r = 0; r < 4; ++r) {
        const int lrow = lrow0 + r;
        if (lrow < rowlim) {
          const size_t g = (size_t)(base + yb * 256 + lrow);
#pragma unroll
          for (int nf = 0; nf < 4; ++nf) {
            const int col = bx * 256 + wn * 64 + nf * 16 + lr;
            ro[g * DIMN + col] = f2bf(acc[m][nf][r]);
          }
        }
      }
    }
  }
#undef RD_A
#undef RD_B
#undef MFMA16
#undef VMW
#undef BARR
#undef LGKM0
}

// ---------------- combine: out[t] += w0*ro[g0] + w1*ro[g1] ----------------
__global__ __launch_bounds__(256) void k_combine(const unsigned short* __restrict__ ro,
                                                 const int* __restrict__ pos,
                                                 const float* __restrict__ tw,
                                                 float* __restrict__ out) {
  const int t = blockIdx.x;
  const int g0 = pos[2 * t], g1 = pos[2 * t + 1];
  const float w0 = tw[2 * t], w1 = tw[2 * t + 1];
  const int c = threadIdx.x * 4;
  ushort4 r0 = *(const ushort4*)(ro + (size_t)g0 * DIMN + c);
  ushort4 r1 = *(const ushort4*)(ro + (size_t)g1 * DIMN + c);
  float4 o = *(float4*)(out + (size_t)t * DIMN + c);
  o.x += w0 * bf2f(r0.x) + w1 * bf2f(r1.x);
  o.y += w0 * bf2f(r0.y) + w1 * bf2f(r1.y);
  o.z += w0 * bf2f(r0.z) + w1 * bf2f(r1.z);
  o.w += w0 * bf2f(r0.w) + w1 * bf2f(r1.w);
  *(float4*)(out + (size_t)t * DIMN + c) = o;
}

// ---------------- ws layout ----------------
static const size_t OFF_XB    = 0;
static const size_t OFF_W13   = OFF_XB + (size_t)TOK * DIMN * 2;
static const size_t OFF_W2    = OFF_W13 + (size_t)NSLOT * 2560 * DIMN * 2;
static const size_t OFF_H     = OFF_W2 + (size_t)NSLOT * DIMN * HID * 2;
// ro (RCAPG x DIMN bf16 = 36.2 MB) aliases w13b (52.4 MB): w13b dead after gemm1,
// gemm2g (ro writer) runs strictly after gemm1 in stream order.
static const size_t OFF_RO    = OFF_W13;
static const size_t OFF_GLIST = OFF_H + (size_t)(2 * TOK + RCAP) * HID * 2;
static const size_t OFF_POS   = OFF_GLIST + (size_t)RCAPG * 4;
static const size_t OFF_TIDX  = OFF_POS + (size_t)TOK * 2 * 4;
static const size_t OFF_TW    = OFF_TIDX + (size_t)TOK * 2 * 4;
static const size_t OFF_ENTP  = OFF_TW + (size_t)TOK * 2 * 4;
static const size_t OFF_CNT   = OFF_ENTP + (size_t)NGATE * 4;
static const size_t OFF_CNT2  = OFF_CNT + 32;
static const size_t OFF_ROFF  = OFF_CNT2 + 32;
static const size_t OFF_CPAD  = OFF_ROFF + 32;

extern "C" void kernel_launch(void* const* d_in, const int* in_sizes, int n_in,
                              void* d_out, int out_size, void* d_ws, size_t ws_size,
                              hipStream_t stream) {
  const float* x    = (const float*)d_in[0];
  const float* emb  = (const float*)d_in[1];
  const float* bias = (const float*)d_in[2];
  const float* w1   = (const float*)d_in[3];
  const float* w2   = (const float*)d_in[4];
  const float* w3   = (const float*)d_in[5];
  const float* sw1  = (const float*)d_in[6];
  const float* sw2  = (const float*)d_in[7];
  const float* sw3  = (const float*)d_in[8];
  float* out = (float*)d_out;
  char* ws = (char*)d_ws;
  unsigned short* xb   = (unsigned short*)(ws + OFF_XB);
  unsigned short* w13b = (unsigned short*)(ws + OFF_W13);
  unsigned short* w2b  = (unsigned short*)(ws + OFF_W2);
  unsigned short* h    = (unsigned short*)(ws + OFF_H);
  unsigned short* ro   = (unsigned short*)(ws + OFF_RO);
  int*   glist = (int*)(ws + OFF_GLIST);
  int*   pos   = (int*)(ws + OFF_POS);
  int*   tidx  = (int*)(ws + OFF_TIDX);
  float* tw    = (float*)(ws + OFF_TW);
  float* entp  = (float*)(ws + OFF_ENTP);
  int*   cnt   = (int*)(ws + OFF_CNT);
  int*   cnt2  = (int*)(ws + OFF_CNT2);
  int*   roff  = (int*)(ws + OFF_ROFF);
  int*   cpad  = (int*)(ws + OFF_CPAD);

  hipFuncSetAttribute((const void*)k_gemm1_8ph, hipFuncAttributeMaxDynamicSharedMemorySize, 131072);
  hipFuncSetAttribute((const void*)k_gemm2g, hipFuncAttributeMaxDynamicSharedMemorySize, 131072);

  k_zero<<<(RCAPG + 255) / 256, 256, 0, stream>>>(glist, cnt, cnt2);
  k_cvt_x<<<(TOK * DIMN / 4) / 256, 256, 0, stream>>>(x, xb);
  k_cvt_w<<<dim3(2560 + DIMN, NSLOT), 256, 0, stream>>>(w1, w3, sw1, sw3, w2, sw2, w13b, w2b);
  k_gate<<<NGATE, 256, 0, stream>>>(x, emb, bias, tidx, tw, entp);
  k_count<<<TOK / 256, 256, 0, stream>>>(tidx, cnt);
  k_offsets<<<1, 256, 0, stream>>>(cnt, roff, cpad, entp, out + (size_t)TOK * DIMN);
  k_scatter<<<TOK / 256, 256, 0, stream>>>(tidx, roff, cnt2, glist, pos);
  k_gemm1_8ph<<<dim3(10, TOK / 256, NSLOT), 512, 131072, stream>>>(xb, w13b, h, glist, roff, cpad);
  k_gemm2g<<<dim3(DIMN / 256, TOK / 256, 1 + NEXP), 512, 131072, stream>>>(h, w2b, roff, cpad, out, ro);
  k_combine<<<TOK, 256, 0, stream>>>(ro, pos, tw, out);
}